// Round 1
// baseline (1018.654 us; speedup 1.0000x reference)
//
#include <hip/hip_runtime.h>
#include <math.h>

#define NN 50000
#define NE 1600000
#define FIN 9
#define DD 128
#define NG 64
#define LN_EPS 1e-5f

// ---------------------------------------------------------------- CSR build
__global__ __launch_bounds__(256) void k_hist(const int* __restrict__ dst,
                                              int* __restrict__ cnt) {
  int i = blockIdx.x * blockDim.x + threadIdx.x;
  if (i < NE) {
    int d = dst[i];
    if ((unsigned)d < NN) atomicAdd(&cnt[d], 1);
  }
}

__global__ __launch_bounds__(1024) void k_scan(const int* __restrict__ cnt,
                                               int* __restrict__ rowptr) {
  __shared__ int part[1024];
  const int t = threadIdx.x;
  const int CH = (NN + 1023) / 1024;  // 49
  int lo = t * CH, hi = min(lo + CH, NN);
  int s = 0;
  for (int i = lo; i < hi; ++i) s += cnt[i];
  part[t] = s;
  __syncthreads();
  for (int off = 1; off < 1024; off <<= 1) {
    int v = (t >= off) ? part[t - off] : 0;
    __syncthreads();
    part[t] += v;
    __syncthreads();
  }
  int run = (t == 0) ? 0 : part[t - 1];
  for (int i = lo; i < hi; ++i) { rowptr[i] = run; run += cnt[i]; }
  if (t == 1023) rowptr[NN] = run;
}

__global__ __launch_bounds__(256) void k_scatter(const int* __restrict__ src,
                                                 const int* __restrict__ dst,
                                                 const int* __restrict__ rowptr,
                                                 int* __restrict__ cursor,
                                                 int* __restrict__ csr) {
  int i = blockIdx.x * blockDim.x + threadIdx.x;
  if (i < NE) {
    int d = dst[i];
    if ((unsigned)d < NN) {
      int pos = rowptr[d] + atomicAdd(&cursor[d], 1);
      int s = src[i];
      csr[pos] = ((unsigned)s < NN) ? s : 0;
    }
  }
}

__global__ __launch_bounds__(128) void k_gstart(const int* __restrict__ batch,
                                                int* __restrict__ gstart) {
  int g = threadIdx.x;
  if (g > NG) return;
  int lo = 0, hi = NN;
  while (lo < hi) {
    int mid = (lo + hi) >> 1;
    if (batch[mid] < g) lo = mid + 1; else hi = mid;
  }
  gstart[g] = lo;
}

// ---------------------------------------------------------------- embed: relu(LN(x@W+b))
__global__ __launch_bounds__(256) void k_embed(const float* __restrict__ x,
                                               const float* __restrict__ W,
                                               const float* __restrict__ b,
                                               const float* __restrict__ gamma,
                                               const float* __restrict__ beta,
                                               float* __restrict__ hout) {
  const int wid = threadIdx.x >> 6;
  const int lane = threadIdx.x & 63;
  const int node = blockIdx.x * 4 + wid;
  if (node >= NN) return;
  float xr[FIN];
#pragma unroll
  for (int k = 0; k < FIN; ++k) xr[k] = x[node * FIN + k];
  const int c0 = lane, c1 = lane + 64;
  float a0 = b[c0], a1 = b[c1];
#pragma unroll
  for (int k = 0; k < FIN; ++k) {
    a0 += xr[k] * W[k * DD + c0];
    a1 += xr[k] * W[k * DD + c1];
  }
  float s = a0 + a1;
#pragma unroll
  for (int m = 1; m < 64; m <<= 1) s += __shfl_xor(s, m, 64);
  float mean = s * (1.f / DD);
  float d0 = a0 - mean, d1 = a1 - mean;
  float v = d0 * d0 + d1 * d1;
#pragma unroll
  for (int m = 1; m < 64; m <<= 1) v += __shfl_xor(v, m, 64);
  float r = rsqrtf(v * (1.f / DD) + LN_EPS);
  hout[(size_t)node * DD + c0] = fmaxf(d0 * r * gamma[c0] + beta[c0], 0.f);
  hout[(size_t)node * DD + c1] = fmaxf(d1 * r * gamma[c1] + beta[c1], 0.f);
}

// ---------------------------------------------------------------- scatter-mean (gather form)
__global__ __launch_bounds__(256) void k_aggr(const float* __restrict__ h,
                                              const int* __restrict__ rowptr,
                                              const int* __restrict__ csr,
                                              float* __restrict__ hm) {
  const int wid = threadIdx.x >> 6;
  const int lane = threadIdx.x & 63;
  const int node = blockIdx.x * 4 + wid;
  if (node >= NN) return;
  const int beg = rowptr[node], end = rowptr[node + 1];
  const float2* __restrict__ h2 = reinterpret_cast<const float2*>(h);
  float a0 = 0.f, a1 = 0.f;
  for (int base = beg; base < end; base += 64) {
    int m = min(64, end - base);
    int myidx = (lane < m) ? csr[base + lane] : 0;
    for (int j = 0; j < m; ++j) {
      int s = __shfl(myidx, j, 64);
      float2 v = h2[(size_t)s * 64 + lane];
      a0 += v.x;
      a1 += v.y;
    }
  }
  float inv = 1.f / (float)max(end - beg, 1);
  float2 o;
  o.x = a0 * inv;
  o.y = a1 * inv;
  reinterpret_cast<float2*>(hm)[(size_t)node * 64 + lane] = o;
}

// ---------------------------------------------------------------- fused linear(256->128)+LN+ReLU
// 32 nodes/block, 256 threads: cg=tid&31 (4 channels), ng=tid>>5 (4 nodes)
__global__ __launch_bounds__(256) void k_lin(const float* __restrict__ hA,
                                             const float* __restrict__ hB,
                                             const float* __restrict__ W,
                                             const float* __restrict__ bias,
                                             const float* __restrict__ gamma,
                                             const float* __restrict__ beta,
                                             float* __restrict__ out) {
  __shared__ float At[256 * 32];   // At[k*32 + n] (transposed A tile)
  __shared__ float Ws[64 * 128];   // Ws[dk*128 + c] (K-chunk of W)
  const int tid = threadIdx.x;
  const int nodeBase = blockIdx.x * 32;

  // stage A transposed: item i -> n = i&31, q = i>>5 (float4 index in 256-float concat row)
  // lanes carry distinct n  => transpose LDS writes land in distinct banks (2-way dup = free)
#pragma unroll
  for (int it = 0; it < 8; ++it) {
    int i = tid + it * 256;
    int n = i & 31;
    int q = i >> 5;
    int gn = nodeBase + n;
    float4 v = make_float4(0.f, 0.f, 0.f, 0.f);
    if (gn < NN) {
      v = (q < 32) ? reinterpret_cast<const float4*>(hA + (size_t)gn * DD)[q]
                   : reinterpret_cast<const float4*>(hB + (size_t)gn * DD)[q - 32];
    }
    int k = q * 4;
    At[(k + 0) * 32 + n] = v.x;
    At[(k + 1) * 32 + n] = v.y;
    At[(k + 2) * 32 + n] = v.z;
    At[(k + 3) * 32 + n] = v.w;
  }

  const int cg = tid & 31;
  const int ng = tid >> 5;
  float4 bv = reinterpret_cast<const float4*>(bias)[cg];
  float acc[4][4];
#pragma unroll
  for (int i = 0; i < 4; ++i) {
    acc[i][0] = bv.x; acc[i][1] = bv.y; acc[i][2] = bv.z; acc[i][3] = bv.w;
  }

  for (int kc = 0; kc < 4; ++kc) {
    __syncthreads();  // At writes ready (kc=0) / previous chunk's Ws reads done
#pragma unroll
    for (int it = 0; it < 8; ++it) {
      int i = tid + it * 256;
      int dk = i >> 5;
      int cq = i & 31;
      float4 w = reinterpret_cast<const float4*>(W + (size_t)(kc * 64 + dk) * DD)[cq];
      reinterpret_cast<float4*>(Ws + dk * DD)[cq] = w;
    }
    __syncthreads();
#pragma unroll 8
    for (int dk = 0; dk < 64; ++dk) {
      int k = kc * 64 + dk;
      float4 af = reinterpret_cast<const float4*>(At + k * 32)[ng];
      float4 wf = reinterpret_cast<const float4*>(Ws + dk * DD)[cg];
      float av[4] = {af.x, af.y, af.z, af.w};
      float wv[4] = {wf.x, wf.y, wf.z, wf.w};
#pragma unroll
      for (int i = 0; i < 4; ++i)
#pragma unroll
        for (int j = 0; j < 4; ++j) acc[i][j] += av[i] * wv[j];
    }
  }

  // LN + ReLU epilogue; lanes with same ng (a 32-lane half-wave) hold a node's 128 channels
  float4 gv = reinterpret_cast<const float4*>(gamma)[cg];
  float4 btv = reinterpret_cast<const float4*>(beta)[cg];
  float gj[4] = {gv.x, gv.y, gv.z, gv.w};
  float bj[4] = {btv.x, btv.y, btv.z, btv.w};
#pragma unroll
  for (int i = 0; i < 4; ++i) {
    int gn = nodeBase + ng * 4 + i;
    float s = acc[i][0] + acc[i][1] + acc[i][2] + acc[i][3];
#pragma unroll
    for (int m = 1; m < 32; m <<= 1) s += __shfl_xor(s, m, 64);
    float mean = s * (1.f / DD);
    float t = 0.f;
#pragma unroll
    for (int j = 0; j < 4; ++j) {
      float d = acc[i][j] - mean;
      t += d * d;
    }
#pragma unroll
    for (int m = 1; m < 32; m <<= 1) t += __shfl_xor(t, m, 64);
    float r = rsqrtf(t * (1.f / DD) + LN_EPS);
    if (gn < NN) {
      float4 o;
      o.x = fmaxf((acc[i][0] - mean) * r * gj[0] + bj[0], 0.f);
      o.y = fmaxf((acc[i][1] - mean) * r * gj[1] + bj[1], 0.f);
      o.z = fmaxf((acc[i][2] - mean) * r * gj[2] + bj[2], 0.f);
      o.w = fmaxf((acc[i][3] - mean) * r * gj[3] + bj[3], 0.f);
      reinterpret_cast<float4*>(out + (size_t)gn * DD)[cg] = o;
    }
  }
}

// ---------------------------------------------------------------- graph pooling (mean+max)
__global__ __launch_bounds__(128) void k_pool(const float* __restrict__ ne,
                                              const int* __restrict__ gstart,
                                              float* __restrict__ gout) {
  const int g = blockIdx.x;
  const int c = threadIdx.x;  // 0..127
  const int beg = gstart[g], end = gstart[g + 1];
  float s = 0.f, mx = -INFINITY;
  for (int n = beg; n < end; ++n) {
    float v = ne[(size_t)n * DD + c];
    s += v;
    mx = fmaxf(mx, v);
  }
  float mean = s / (float)max(end - beg, 1);
  gout[(size_t)g * 256 + c] = mean;
  gout[(size_t)g * 256 + 128 + c] = mx;
}

// ---------------------------------------------------------------- launch
static inline size_t align_up(size_t v, size_t a) { return (v + a - 1) & ~(a - 1); }

extern "C" void kernel_launch(void* const* d_in, const int* in_sizes, int n_in,
                              void* d_out, int out_size, void* d_ws, size_t ws_size,
                              hipStream_t stream) {
  const float* x     = (const float*)d_in[0];
  const int*   ei    = (const int*)d_in[1];
  const int*   batch = (const int*)d_in[2];
  const float* W_emb = (const float*)d_in[3];
  const float* b_emb = (const float*)d_in[4];
  const float* g0    = (const float*)d_in[5];
  const float* bt0   = (const float*)d_in[6];
  const float* Wc1   = (const float*)d_in[7];
  const float* bc1   = (const float*)d_in[8];
  const float* g1    = (const float*)d_in[9];
  const float* bt1   = (const float*)d_in[10];
  const float* Wc2   = (const float*)d_in[11];
  const float* bc2   = (const float*)d_in[12];
  const float* g2    = (const float*)d_in[13];
  const float* bt2   = (const float*)d_in[14];
  const float* Wc3   = (const float*)d_in[15];
  const float* bc3   = (const float*)d_in[16];
  const float* g3    = (const float*)d_in[17];
  const float* bt3   = (const float*)d_in[18];

  const int* src = ei;
  const int* dst = ei + NE;

  float* out_node  = (float*)d_out;                     // N*D
  float* out_graph = (float*)d_out + (size_t)NN * DD;   // G*256

  char* p = (char*)d_ws;
  auto alloc = [&](size_t bytes) { char* r = p; p += align_up(bytes, 256); return r; };
  int*   rowptr = (int*)alloc((NN + 1) * sizeof(int));
  int*   cursor = (int*)alloc(NN * sizeof(int));
  int*   gstart = (int*)alloc((NG + 1) * sizeof(int));
  int*   csr    = (int*)alloc((size_t)NE * sizeof(int));
  float* h0     = (float*)alloc((size_t)NN * DD * sizeof(float));
  float* h1     = (float*)alloc((size_t)NN * DD * sizeof(float));
  float* hm     = (float*)alloc((size_t)NN * DD * sizeof(float));

  // CSR build (reused by all 3 layers)
  hipMemsetAsync(cursor, 0, NN * sizeof(int), stream);
  k_hist<<<NE / 256, 256, 0, stream>>>(dst, cursor);
  k_scan<<<1, 1024, 0, stream>>>(cursor, rowptr);
  hipMemsetAsync(cursor, 0, NN * sizeof(int), stream);
  k_scatter<<<NE / 256, 256, 0, stream>>>(src, dst, rowptr, cursor, csr);
  k_gstart<<<1, 128, 0, stream>>>(batch, gstart);

  // embed
  k_embed<<<NN / 4, 256, 0, stream>>>(x, W_emb, b_emb, g0, bt0, h0);

  const int LIN_GRID = (NN + 31) / 32;  // 1563
  // layer 1
  k_aggr<<<NN / 4, 256, 0, stream>>>(h0, rowptr, csr, hm);
  k_lin<<<LIN_GRID, 256, 0, stream>>>(h0, hm, Wc1, bc1, g1, bt1, h1);
  // layer 2
  k_aggr<<<NN / 4, 256, 0, stream>>>(h1, rowptr, csr, hm);
  k_lin<<<LIN_GRID, 256, 0, stream>>>(h1, hm, Wc2, bc2, g2, bt2, h0);
  // layer 3
  k_aggr<<<NN / 4, 256, 0, stream>>>(h0, rowptr, csr, hm);
  k_lin<<<LIN_GRID, 256, 0, stream>>>(h0, hm, Wc3, bc3, g3, bt3, out_node);

  // pooling
  k_pool<<<NG, 128, 0, stream>>>(out_node, gstart, out_graph);
}

// Round 2
// 803.763 us; speedup vs baseline: 1.2674x; 1.2674x over previous
//
#include <hip/hip_runtime.h>
#include <math.h>

#define NN 50000
#define NE 1600000
#define FIN 9
#define DD 128
#define NG 64
#define PSEG 16
#define LN_EPS 1e-5f

// ---------------------------------------------------------------- CSR build
__global__ __launch_bounds__(256) void k_hist(const int* __restrict__ dst,
                                              int* __restrict__ cnt) {
  int i = blockIdx.x * blockDim.x + threadIdx.x;
  if (i < NE) {
    int d = dst[i];
    if ((unsigned)d < NN) atomicAdd(&cnt[d], 1);
  }
}

__global__ __launch_bounds__(1024) void k_scan(const int* __restrict__ cnt,
                                               int* __restrict__ rowptr) {
  __shared__ int part[1024];
  const int t = threadIdx.x;
  const int CH = (NN + 1023) / 1024;  // 49
  int lo = t * CH, hi = min(lo + CH, NN);
  int s = 0;
  for (int i = lo; i < hi; ++i) s += cnt[i];
  part[t] = s;
  __syncthreads();
  for (int off = 1; off < 1024; off <<= 1) {
    int v = (t >= off) ? part[t - off] : 0;
    __syncthreads();
    part[t] += v;
    __syncthreads();
  }
  int run = (t == 0) ? 0 : part[t - 1];
  for (int i = lo; i < hi; ++i) { rowptr[i] = run; run += cnt[i]; }
  if (t == 1023) rowptr[NN] = run;
}

__global__ __launch_bounds__(256) void k_scatter(const int* __restrict__ src,
                                                 const int* __restrict__ dst,
                                                 const int* __restrict__ rowptr,
                                                 int* __restrict__ cursor,
                                                 int* __restrict__ csr) {
  int i = blockIdx.x * blockDim.x + threadIdx.x;
  if (i < NE) {
    int d = dst[i];
    if ((unsigned)d < NN) {
      int pos = rowptr[d] + atomicAdd(&cursor[d], 1);
      int s = src[i];
      csr[pos] = ((unsigned)s < NN) ? s : 0;
    }
  }
}

__global__ __launch_bounds__(128) void k_gstart(const int* __restrict__ batch,
                                                int* __restrict__ gstart) {
  int g = threadIdx.x;
  if (g > NG) return;
  int lo = 0, hi = NN;
  while (lo < hi) {
    int mid = (lo + hi) >> 1;
    if (batch[mid] < g) lo = mid + 1; else hi = mid;
  }
  gstart[g] = lo;
}

// ---------------------------------------------------------------- embed: relu(LN(x@W+b))
__global__ __launch_bounds__(256) void k_embed(const float* __restrict__ x,
                                               const float* __restrict__ W,
                                               const float* __restrict__ b,
                                               const float* __restrict__ gamma,
                                               const float* __restrict__ beta,
                                               float* __restrict__ hout) {
  const int wid = threadIdx.x >> 6;
  const int lane = threadIdx.x & 63;
  const int node = blockIdx.x * 4 + wid;
  if (node >= NN) return;
  float xr[FIN];
#pragma unroll
  for (int k = 0; k < FIN; ++k) xr[k] = x[node * FIN + k];
  const int c0 = lane, c1 = lane + 64;
  float a0 = b[c0], a1 = b[c1];
#pragma unroll
  for (int k = 0; k < FIN; ++k) {
    a0 += xr[k] * W[k * DD + c0];
    a1 += xr[k] * W[k * DD + c1];
  }
  float s = a0 + a1;
#pragma unroll
  for (int m = 1; m < 64; m <<= 1) s += __shfl_xor(s, m, 64);
  float mean = s * (1.f / DD);
  float d0 = a0 - mean, d1 = a1 - mean;
  float v = d0 * d0 + d1 * d1;
#pragma unroll
  for (int m = 1; m < 64; m <<= 1) v += __shfl_xor(v, m, 64);
  float r = rsqrtf(v * (1.f / DD) + LN_EPS);
  hout[(size_t)node * DD + c0] = fmaxf(d0 * r * gamma[c0] + beta[c0], 0.f);
  hout[(size_t)node * DD + c1] = fmaxf(d1 * r * gamma[c1] + beta[c1], 0.f);
}

// ---------------------------------------------------------------- scatter-mean (gather form)
// one node per 32-lane half-wave; float4 loads (16B/lane); 4x unrolled neighbor loop
__global__ __launch_bounds__(256) void k_aggr(const float* __restrict__ h,
                                              const int* __restrict__ rowptr,
                                              const int* __restrict__ csr,
                                              float* __restrict__ hm) {
  const int half = threadIdx.x >> 5;
  const int lane = threadIdx.x & 31;
  const int node = blockIdx.x * 8 + half;
  if (node >= NN) return;
  const int beg = rowptr[node], end = rowptr[node + 1];
  const float4* __restrict__ h4 = reinterpret_cast<const float4*>(h);
  float ax = 0.f, ay = 0.f, az = 0.f, aw = 0.f;
  for (int base = beg; base < end; base += 32) {
    int m = min(32, end - base);
    int myidx = (lane < m) ? csr[base + lane] : 0;
    int j = 0;
    for (; j + 4 <= m; j += 4) {
      int s0 = __shfl(myidx, j + 0, 32);
      int s1 = __shfl(myidx, j + 1, 32);
      int s2 = __shfl(myidx, j + 2, 32);
      int s3 = __shfl(myidx, j + 3, 32);
      float4 v0 = h4[(size_t)s0 * 32 + lane];
      float4 v1 = h4[(size_t)s1 * 32 + lane];
      float4 v2 = h4[(size_t)s2 * 32 + lane];
      float4 v3 = h4[(size_t)s3 * 32 + lane];
      ax += v0.x + v1.x + v2.x + v3.x;
      ay += v0.y + v1.y + v2.y + v3.y;
      az += v0.z + v1.z + v2.z + v3.z;
      aw += v0.w + v1.w + v2.w + v3.w;
    }
    for (; j < m; ++j) {
      int s0 = __shfl(myidx, j, 32);
      float4 v = h4[(size_t)s0 * 32 + lane];
      ax += v.x; ay += v.y; az += v.z; aw += v.w;
    }
  }
  float inv = 1.f / (float)max(end - beg, 1);
  float4 o;
  o.x = ax * inv; o.y = ay * inv; o.z = az * inv; o.w = aw * inv;
  reinterpret_cast<float4*>(hm)[(size_t)node * 32 + lane] = o;
}

// ---------------------------------------------------------------- fused linear(256->128)+LN+ReLU
__global__ __launch_bounds__(256) void k_lin(const float* __restrict__ hA,
                                             const float* __restrict__ hB,
                                             const float* __restrict__ W,
                                             const float* __restrict__ bias,
                                             const float* __restrict__ gamma,
                                             const float* __restrict__ beta,
                                             float* __restrict__ out) {
  __shared__ float At[256 * 32];   // At[k*32 + n]
  __shared__ float Ws[64 * 128];   // Ws[dk*128 + c]
  const int tid = threadIdx.x;
  const int nodeBase = blockIdx.x * 32;

#pragma unroll
  for (int it = 0; it < 8; ++it) {
    int i = tid + it * 256;
    int n = i & 31;
    int q = i >> 5;
    int gn = nodeBase + n;
    float4 v = make_float4(0.f, 0.f, 0.f, 0.f);
    if (gn < NN) {
      v = (q < 32) ? reinterpret_cast<const float4*>(hA + (size_t)gn * DD)[q]
                   : reinterpret_cast<const float4*>(hB + (size_t)gn * DD)[q - 32];
    }
    int k = q * 4;
    At[(k + 0) * 32 + n] = v.x;
    At[(k + 1) * 32 + n] = v.y;
    At[(k + 2) * 32 + n] = v.z;
    At[(k + 3) * 32 + n] = v.w;
  }

  const int cg = tid & 31;
  const int ng = tid >> 5;
  float4 bv = reinterpret_cast<const float4*>(bias)[cg];
  float acc[4][4];
#pragma unroll
  for (int i = 0; i < 4; ++i) {
    acc[i][0] = bv.x; acc[i][1] = bv.y; acc[i][2] = bv.z; acc[i][3] = bv.w;
  }

  for (int kc = 0; kc < 4; ++kc) {
    __syncthreads();
#pragma unroll
    for (int it = 0; it < 8; ++it) {
      int i = tid + it * 256;
      int dk = i >> 5;
      int cq = i & 31;
      float4 w = reinterpret_cast<const float4*>(W + (size_t)(kc * 64 + dk) * DD)[cq];
      reinterpret_cast<float4*>(Ws + dk * DD)[cq] = w;
    }
    __syncthreads();
#pragma unroll 8
    for (int dk = 0; dk < 64; ++dk) {
      int k = kc * 64 + dk;
      float4 af = reinterpret_cast<const float4*>(At + k * 32)[ng];
      float4 wf = reinterpret_cast<const float4*>(Ws + dk * DD)[cg];
      float av[4] = {af.x, af.y, af.z, af.w};
      float wv[4] = {wf.x, wf.y, wf.z, wf.w};
#pragma unroll
      for (int i = 0; i < 4; ++i)
#pragma unroll
        for (int j = 0; j < 4; ++j) acc[i][j] += av[i] * wv[j];
    }
  }

  float4 gv = reinterpret_cast<const float4*>(gamma)[cg];
  float4 btv = reinterpret_cast<const float4*>(beta)[cg];
  float gj[4] = {gv.x, gv.y, gv.z, gv.w};
  float bj[4] = {btv.x, btv.y, btv.z, btv.w};
#pragma unroll
  for (int i = 0; i < 4; ++i) {
    int gn = nodeBase + ng * 4 + i;
    float s = acc[i][0] + acc[i][1] + acc[i][2] + acc[i][3];
#pragma unroll
    for (int m = 1; m < 32; m <<= 1) s += __shfl_xor(s, m, 64);
    float mean = s * (1.f / DD);
    float t = 0.f;
#pragma unroll
    for (int j = 0; j < 4; ++j) {
      float d = acc[i][j] - mean;
      t += d * d;
    }
#pragma unroll
    for (int m = 1; m < 32; m <<= 1) t += __shfl_xor(t, m, 64);
    float r = rsqrtf(t * (1.f / DD) + LN_EPS);
    if (gn < NN) {
      float4 o;
      o.x = fmaxf((acc[i][0] - mean) * r * gj[0] + bj[0], 0.f);
      o.y = fmaxf((acc[i][1] - mean) * r * gj[1] + bj[1], 0.f);
      o.z = fmaxf((acc[i][2] - mean) * r * gj[2] + bj[2], 0.f);
      o.w = fmaxf((acc[i][3] - mean) * r * gj[3] + bj[3], 0.f);
      reinterpret_cast<float4*>(out + (size_t)gn * DD)[cg] = o;
    }
  }
}

// ---------------------------------------------------------------- graph pooling (mean+max)
// stage 1: partials over (graph, segment); stage 2: reduce segments
__global__ __launch_bounds__(128) void k_pool1(const float* __restrict__ ne,
                                               const int* __restrict__ gstart,
                                               float* __restrict__ part) {
  const int g = blockIdx.x / PSEG;
  const int sg = blockIdx.x % PSEG;
  const int c = threadIdx.x;  // 0..127
  const int beg = gstart[g], end = gstart[g + 1];
  const int len = end - beg;
  const int per = (len + PSEG - 1) / PSEG;
  const int n0 = beg + sg * per;
  const int n1 = min(n0 + per, end);
  float s = 0.f, mx = -INFINITY;
  for (int n = n0; n < n1; ++n) {
    float v = ne[(size_t)n * DD + c];
    s += v;
    mx = fmaxf(mx, v);
  }
  part[(size_t)(g * PSEG + sg) * 256 + c] = s;
  part[(size_t)(g * PSEG + sg) * 256 + 128 + c] = mx;
}

__global__ __launch_bounds__(256) void k_pool2(const float* __restrict__ part,
                                               const int* __restrict__ gstart,
                                               float* __restrict__ gout) {
  const int g = blockIdx.x;
  const int c = threadIdx.x;  // 0..255
  const bool isMax = c >= 128;
  float acc = isMax ? -INFINITY : 0.f;
  for (int sg = 0; sg < PSEG; ++sg) {
    float v = part[(size_t)(g * PSEG + sg) * 256 + c];
    acc = isMax ? fmaxf(acc, v) : (acc + v);
  }
  if (!isMax) acc /= (float)max(gstart[g + 1] - gstart[g], 1);
  gout[(size_t)g * 256 + c] = acc;
}

// ---------------------------------------------------------------- launch
static inline size_t align_up(size_t v, size_t a) { return (v + a - 1) & ~(a - 1); }

extern "C" void kernel_launch(void* const* d_in, const int* in_sizes, int n_in,
                              void* d_out, int out_size, void* d_ws, size_t ws_size,
                              hipStream_t stream) {
  const float* x     = (const float*)d_in[0];
  const int*   ei    = (const int*)d_in[1];
  const int*   batch = (const int*)d_in[2];
  const float* W_emb = (const float*)d_in[3];
  const float* b_emb = (const float*)d_in[4];
  const float* g0    = (const float*)d_in[5];
  const float* bt0   = (const float*)d_in[6];
  const float* Wc1   = (const float*)d_in[7];
  const float* bc1   = (const float*)d_in[8];
  const float* g1    = (const float*)d_in[9];
  const float* bt1   = (const float*)d_in[10];
  const float* Wc2   = (const float*)d_in[11];
  const float* bc2   = (const float*)d_in[12];
  const float* g2    = (const float*)d_in[13];
  const float* bt2   = (const float*)d_in[14];
  const float* Wc3   = (const float*)d_in[15];
  const float* bc3   = (const float*)d_in[16];
  const float* g3    = (const float*)d_in[17];
  const float* bt3   = (const float*)d_in[18];

  const int* src = ei;
  const int* dst = ei + NE;

  float* out_node  = (float*)d_out;                     // N*D
  float* out_graph = (float*)d_out + (size_t)NN * DD;   // G*256

  char* p = (char*)d_ws;
  auto alloc = [&](size_t bytes) { char* r = p; p += align_up(bytes, 256); return r; };
  int*   rowptr = (int*)alloc((NN + 1) * sizeof(int));
  int*   cursor = (int*)alloc(NN * sizeof(int));
  int*   gstart = (int*)alloc((NG + 1) * sizeof(int));
  int*   csr    = (int*)alloc((size_t)NE * sizeof(int));
  float* h0     = (float*)alloc((size_t)NN * DD * sizeof(float));
  float* h1     = (float*)alloc((size_t)NN * DD * sizeof(float));
  float* hm     = (float*)alloc((size_t)NN * DD * sizeof(float));
  float* ppart  = (float*)alloc((size_t)NG * PSEG * 256 * sizeof(float));

  // CSR build (reused by all 3 layers)
  hipMemsetAsync(cursor, 0, NN * sizeof(int), stream);
  k_hist<<<NE / 256, 256, 0, stream>>>(dst, cursor);
  k_scan<<<1, 1024, 0, stream>>>(cursor, rowptr);
  hipMemsetAsync(cursor, 0, NN * sizeof(int), stream);
  k_scatter<<<NE / 256, 256, 0, stream>>>(src, dst, rowptr, cursor, csr);
  k_gstart<<<1, 128, 0, stream>>>(batch, gstart);

  // embed
  k_embed<<<NN / 4, 256, 0, stream>>>(x, W_emb, b_emb, g0, bt0, h0);

  const int LIN_GRID = (NN + 31) / 32;  // 1563
  const int AGGR_GRID = (NN + 7) / 8;   // 6250
  // layer 1
  k_aggr<<<AGGR_GRID, 256, 0, stream>>>(h0, rowptr, csr, hm);
  k_lin<<<LIN_GRID, 256, 0, stream>>>(h0, hm, Wc1, bc1, g1, bt1, h1);
  // layer 2
  k_aggr<<<AGGR_GRID, 256, 0, stream>>>(h1, rowptr, csr, hm);
  k_lin<<<LIN_GRID, 256, 0, stream>>>(h1, hm, Wc2, bc2, g2, bt2, h0);
  // layer 3
  k_aggr<<<AGGR_GRID, 256, 0, stream>>>(h0, rowptr, csr, hm);
  k_lin<<<LIN_GRID, 256, 0, stream>>>(h0, hm, Wc3, bc3, g3, bt3, out_node);

  // pooling
  k_pool1<<<NG * PSEG, 128, 0, stream>>>(out_node, gstart, ppart);
  k_pool2<<<NG, 256, 0, stream>>>(ppart, gstart, out_graph);
}

// Round 3
// 558.038 us; speedup vs baseline: 1.8254x; 1.4403x over previous
//
#include <hip/hip_runtime.h>
#include <hip/hip_bf16.h>
#include <math.h>

#define NN 50000
#define NNP 50048          // padded rows (782 blocks * 64)
#define NE 1600000
#define FIN 9
#define DD 128
#define NG 64
#define PSEG 16
#define LN_EPS 1e-5f

typedef __attribute__((ext_vector_type(8))) short bf16x8;
typedef __attribute__((ext_vector_type(4))) float f32x4;

static __device__ __forceinline__ float b2f(unsigned short u) {
  return __uint_as_float(((unsigned)u) << 16);
}
static __device__ __forceinline__ unsigned short f2b(float f) {
  __hip_bfloat16 h = __float2bfloat16(f);
  return __builtin_bit_cast(unsigned short, h);
}

// ---------------------------------------------------------------- CSR build
__global__ __launch_bounds__(256) void k_hist(const int* __restrict__ dst,
                                              int* __restrict__ cnt) {
  int i = blockIdx.x * blockDim.x + threadIdx.x;
  if (i < NE) {
    int d = dst[i];
    if ((unsigned)d < NN) atomicAdd(&cnt[d], 1);
  }
}

__global__ __launch_bounds__(1024) void k_scan(const int* __restrict__ cnt,
                                               int* __restrict__ rowptr) {
  __shared__ int part[1024];
  const int t = threadIdx.x;
  const int CH = (NN + 1023) / 1024;  // 49
  int lo = t * CH, hi = min(lo + CH, NN);
  int s = 0;
  for (int i = lo; i < hi; ++i) s += cnt[i];
  part[t] = s;
  __syncthreads();
  for (int off = 1; off < 1024; off <<= 1) {
    int v = (t >= off) ? part[t - off] : 0;
    __syncthreads();
    part[t] += v;
    __syncthreads();
  }
  int run = (t == 0) ? 0 : part[t - 1];
  for (int i = lo; i < hi; ++i) { rowptr[i] = run; run += cnt[i]; }
  if (t == 1023) rowptr[NN] = run;
}

__global__ __launch_bounds__(256) void k_scatter(const int* __restrict__ src,
                                                 const int* __restrict__ dst,
                                                 const int* __restrict__ rowptr,
                                                 int* __restrict__ cursor,
                                                 int* __restrict__ csr) {
  int i = blockIdx.x * blockDim.x + threadIdx.x;
  if (i < NE) {
    int d = dst[i];
    if ((unsigned)d < NN) {
      int pos = rowptr[d] + atomicAdd(&cursor[d], 1);
      int s = src[i];
      csr[pos] = ((unsigned)s < NN) ? s : 0;
    }
  }
}

__global__ __launch_bounds__(128) void k_gstart(const int* __restrict__ batch,
                                                int* __restrict__ gstart) {
  int g = threadIdx.x;
  if (g > NG) return;
  int lo = 0, hi = NN;
  while (lo < hi) {
    int mid = (lo + hi) >> 1;
    if (batch[mid] < g) lo = mid + 1; else hi = mid;
  }
  gstart[g] = lo;
}

// ---------------------------------------------------------------- W^T bf16 (Wt[n][k] = W[k][n])
__global__ __launch_bounds__(512) void k_wt(const float* __restrict__ W,
                                            unsigned short* __restrict__ Wt) {
  int idx = blockIdx.x * 512 + threadIdx.x;  // 0..32767
  int k = idx >> 7;
  int n = idx & 127;
  Wt[n * 256 + k] = f2b(W[k * DD + n]);
}

// ---------------------------------------------------------------- embed: relu(LN(x@W+b)) -> bf16
__global__ __launch_bounds__(256) void k_embed(const float* __restrict__ x,
                                               const float* __restrict__ W,
                                               const float* __restrict__ b,
                                               const float* __restrict__ gamma,
                                               const float* __restrict__ beta,
                                               unsigned short* __restrict__ hout) {
  const int wid = threadIdx.x >> 6;
  const int lane = threadIdx.x & 63;
  const int node = blockIdx.x * 4 + wid;
  if (node >= NN) return;
  float xr[FIN];
#pragma unroll
  for (int k = 0; k < FIN; ++k) xr[k] = x[node * FIN + k];
  const int c0 = lane, c1 = lane + 64;
  float a0 = b[c0], a1 = b[c1];
#pragma unroll
  for (int k = 0; k < FIN; ++k) {
    a0 += xr[k] * W[k * DD + c0];
    a1 += xr[k] * W[k * DD + c1];
  }
  float s = a0 + a1;
#pragma unroll
  for (int m = 1; m < 64; m <<= 1) s += __shfl_xor(s, m, 64);
  float mean = s * (1.f / DD);
  float d0 = a0 - mean, d1 = a1 - mean;
  float v = d0 * d0 + d1 * d1;
#pragma unroll
  for (int m = 1; m < 64; m <<= 1) v += __shfl_xor(v, m, 64);
  float r = rsqrtf(v * (1.f / DD) + LN_EPS);
  hout[(size_t)node * DD + c0] = f2b(fmaxf(d0 * r * gamma[c0] + beta[c0], 0.f));
  hout[(size_t)node * DD + c1] = f2b(fmaxf(d1 * r * gamma[c1] + beta[c1], 0.f));
}

// ---------------------------------------------------------------- scatter-mean (bf16 gather)
// one node per 32-lane half-wave; ushort4 (8B) loads; 4x unrolled neighbor loop
__global__ __launch_bounds__(256) void k_aggr(const unsigned short* __restrict__ hb,
                                              const int* __restrict__ rowptr,
                                              const int* __restrict__ csr,
                                              unsigned short* __restrict__ hmb) {
  const int half = threadIdx.x >> 5;
  const int lane = threadIdx.x & 31;
  const int node = blockIdx.x * 8 + half;
  if (node >= NN) return;
  const int beg = rowptr[node], end = rowptr[node + 1];
  const ushort4* __restrict__ h4 = reinterpret_cast<const ushort4*>(hb);
  float ax = 0.f, ay = 0.f, az = 0.f, aw = 0.f;
  for (int base = beg; base < end; base += 32) {
    int m = min(32, end - base);
    int myidx = (lane < m) ? csr[base + lane] : 0;
    int j = 0;
    for (; j + 4 <= m; j += 4) {
      int s0 = __shfl(myidx, j + 0, 32);
      int s1 = __shfl(myidx, j + 1, 32);
      int s2 = __shfl(myidx, j + 2, 32);
      int s3 = __shfl(myidx, j + 3, 32);
      ushort4 v0 = h4[(size_t)s0 * 32 + lane];
      ushort4 v1 = h4[(size_t)s1 * 32 + lane];
      ushort4 v2 = h4[(size_t)s2 * 32 + lane];
      ushort4 v3 = h4[(size_t)s3 * 32 + lane];
      ax += b2f(v0.x) + b2f(v1.x) + b2f(v2.x) + b2f(v3.x);
      ay += b2f(v0.y) + b2f(v1.y) + b2f(v2.y) + b2f(v3.y);
      az += b2f(v0.z) + b2f(v1.z) + b2f(v2.z) + b2f(v3.z);
      aw += b2f(v0.w) + b2f(v1.w) + b2f(v2.w) + b2f(v3.w);
    }
    for (; j < m; ++j) {
      int s0 = __shfl(myidx, j, 32);
      ushort4 v = h4[(size_t)s0 * 32 + lane];
      ax += b2f(v.x); ay += b2f(v.y); az += b2f(v.z); aw += b2f(v.w);
    }
  }
  float inv = 1.f / (float)max(end - beg, 1);
  ushort4 o;
  o.x = f2b(ax * inv); o.y = f2b(ay * inv); o.z = f2b(az * inv); o.w = f2b(aw * inv);
  reinterpret_cast<ushort4*>(hmb)[(size_t)node * 32 + lane] = o;
}

// ---------------------------------------------------------------- MFMA linear(256->128)+LN+ReLU
// block=256 (4 waves), 64 nodes/block (16 per wave). K=256 (128 self + 128 mean).
// A rows = nodes (bf16, contiguous K); B = W^T rows (contiguous K) -> m97-verified pattern.
template <int OUT_BF16>
__global__ __launch_bounds__(256) void k_lin_mfma(const unsigned short* __restrict__ hb,
                                                  const unsigned short* __restrict__ hmb,
                                                  const unsigned short* __restrict__ Wt,
                                                  const float* __restrict__ bias,
                                                  const float* __restrict__ gamma,
                                                  const float* __restrict__ beta,
                                                  void* __restrict__ outv) {
  const int tid = threadIdx.x;
  const int w = tid >> 6;
  const int l = tid & 63;
  const int c16 = l & 15;       // A-row / B-col / C-col within 16-tile
  const int kg = l >> 4;        // k-group 0..3 (8 contiguous k each)
  const int rowBase = blockIdx.x * 64 + w * 16;

  f32x4 acc[8];
#pragma unroll
  for (int t = 0; t < 8; ++t) acc[t] = (f32x4){0.f, 0.f, 0.f, 0.f};

  const unsigned short* arow_self = hb + (size_t)(rowBase + c16) * DD;
  const unsigned short* arow_mean = hmb + (size_t)(rowBase + c16) * DD;

#pragma unroll
  for (int kc = 0; kc < 8; ++kc) {
    const unsigned short* arow = (kc < 4) ? arow_self : arow_mean;
    bf16x8 a = *reinterpret_cast<const bf16x8*>(arow + (kc & 3) * 32 + kg * 8);
#pragma unroll
    for (int t = 0; t < 8; ++t) {
      bf16x8 b = *reinterpret_cast<const bf16x8*>(
          Wt + (size_t)(t * 16 + c16) * 256 + kc * 32 + kg * 8);
      acc[t] = __builtin_amdgcn_mfma_f32_16x16x32_bf16(a, b, acc[t], 0, 0, 0);
    }
  }

  // epilogue: bias + LN + ReLU.  C/D: col = t*16 + (l&15), row = (l>>4)*4 + i
  float bv[8], gv[8], btv[8];
#pragma unroll
  for (int t = 0; t < 8; ++t) {
    int c = t * 16 + c16;
    bv[t] = bias[c]; gv[t] = gamma[c]; btv[t] = beta[c];
  }
#pragma unroll
  for (int t = 0; t < 8; ++t)
#pragma unroll
    for (int i = 0; i < 4; ++i) acc[t][i] += bv[t];

#pragma unroll
  for (int i = 0; i < 4; ++i) {
    float s = 0.f;
#pragma unroll
    for (int t = 0; t < 8; ++t) s += acc[t][i];
#pragma unroll
    for (int m = 1; m < 16; m <<= 1) s += __shfl_xor(s, m, 64);
    float mean = s * (1.f / DD);
    float v = 0.f;
#pragma unroll
    for (int t = 0; t < 8; ++t) {
      float d = acc[t][i] - mean;
      v += d * d;
    }
#pragma unroll
    for (int m = 1; m < 16; m <<= 1) v += __shfl_xor(v, m, 64);
    float r = rsqrtf(v * (1.f / DD) + LN_EPS);
    int onode = rowBase + kg * 4 + i;
    if (onode < NN) {
#pragma unroll
      for (int t = 0; t < 8; ++t) {
        float val = fmaxf((acc[t][i] - mean) * r * gv[t] + btv[t], 0.f);
        int c = t * 16 + c16;
        if (OUT_BF16) {
          ((unsigned short*)outv)[(size_t)onode * DD + c] = f2b(val);
        } else {
          ((float*)outv)[(size_t)onode * DD + c] = val;
        }
      }
    }
  }
}

// ---------------------------------------------------------------- graph pooling (mean+max)
__global__ __launch_bounds__(128) void k_pool1(const float* __restrict__ ne,
                                               const int* __restrict__ gstart,
                                               float* __restrict__ part) {
  const int g = blockIdx.x / PSEG;
  const int sg = blockIdx.x % PSEG;
  const int c = threadIdx.x;  // 0..127
  const int beg = gstart[g], end = gstart[g + 1];
  const int len = end - beg;
  const int per = (len + PSEG - 1) / PSEG;
  const int n0 = beg + sg * per;
  const int n1 = min(n0 + per, end);
  float s = 0.f, mx = -INFINITY;
  for (int n = n0; n < n1; ++n) {
    float v = ne[(size_t)n * DD + c];
    s += v;
    mx = fmaxf(mx, v);
  }
  part[(size_t)(g * PSEG + sg) * 256 + c] = s;
  part[(size_t)(g * PSEG + sg) * 256 + 128 + c] = mx;
}

__global__ __launch_bounds__(256) void k_pool2(const float* __restrict__ part,
                                               const int* __restrict__ gstart,
                                               float* __restrict__ gout) {
  const int g = blockIdx.x;
  const int c = threadIdx.x;  // 0..255
  const bool isMax = c >= 128;
  float acc = isMax ? -INFINITY : 0.f;
  for (int sg = 0; sg < PSEG; ++sg) {
    float v = part[(size_t)(g * PSEG + sg) * 256 + c];
    acc = isMax ? fmaxf(acc, v) : (acc + v);
  }
  if (!isMax) acc /= (float)max(gstart[g + 1] - gstart[g], 1);
  gout[(size_t)g * 256 + c] = acc;
}

// ---------------------------------------------------------------- launch
static inline size_t align_up(size_t v, size_t a) { return (v + a - 1) & ~(a - 1); }

extern "C" void kernel_launch(void* const* d_in, const int* in_sizes, int n_in,
                              void* d_out, int out_size, void* d_ws, size_t ws_size,
                              hipStream_t stream) {
  const float* x     = (const float*)d_in[0];
  const int*   ei    = (const int*)d_in[1];
  const int*   batch = (const int*)d_in[2];
  const float* W_emb = (const float*)d_in[3];
  const float* b_emb = (const float*)d_in[4];
  const float* g0    = (const float*)d_in[5];
  const float* bt0   = (const float*)d_in[6];
  const float* Wc1   = (const float*)d_in[7];
  const float* bc1   = (const float*)d_in[8];
  const float* g1    = (const float*)d_in[9];
  const float* bt1   = (const float*)d_in[10];
  const float* Wc2   = (const float*)d_in[11];
  const float* bc2   = (const float*)d_in[12];
  const float* g2    = (const float*)d_in[13];
  const float* bt2   = (const float*)d_in[14];
  const float* Wc3   = (const float*)d_in[15];
  const float* bc3   = (const float*)d_in[16];
  const float* g3    = (const float*)d_in[17];
  const float* bt3   = (const float*)d_in[18];

  const int* src = ei;
  const int* dst = ei + NE;

  float* out_node  = (float*)d_out;                     // N*D fp32
  float* out_graph = (float*)d_out + (size_t)NN * DD;   // G*256 fp32

  char* p = (char*)d_ws;
  auto alloc = [&](size_t bytes) { char* r = p; p += align_up(bytes, 256); return r; };
  int*            rowptr = (int*)alloc((NN + 1) * sizeof(int));
  int*            cursor = (int*)alloc(NN * sizeof(int));
  int*            gstart = (int*)alloc((NG + 1) * sizeof(int));
  int*            csr    = (int*)alloc((size_t)NE * sizeof(int));
  unsigned short* hba    = (unsigned short*)alloc((size_t)NNP * DD * 2);
  unsigned short* hbb    = (unsigned short*)alloc((size_t)NNP * DD * 2);
  unsigned short* hmb    = (unsigned short*)alloc((size_t)NNP * DD * 2);
  unsigned short* Wt1    = (unsigned short*)alloc(128 * 256 * 2);
  unsigned short* Wt2    = (unsigned short*)alloc(128 * 256 * 2);
  unsigned short* Wt3    = (unsigned short*)alloc(128 * 256 * 2);
  float*          ppart  = (float*)alloc((size_t)NG * PSEG * 256 * sizeof(float));

  // zero pad rows (NNP-NN) so MFMA pad lanes never see NaN garbage
  const size_t padB = (size_t)(NNP - NN) * DD * 2;
  hipMemsetAsync(hba + (size_t)NN * DD, 0, padB, stream);
  hipMemsetAsync(hbb + (size_t)NN * DD, 0, padB, stream);
  hipMemsetAsync(hmb + (size_t)NN * DD, 0, padB, stream);

  // CSR build (reused by all 3 layers)
  hipMemsetAsync(cursor, 0, NN * sizeof(int), stream);
  k_hist<<<NE / 256, 256, 0, stream>>>(dst, cursor);
  k_scan<<<1, 1024, 0, stream>>>(cursor, rowptr);
  hipMemsetAsync(cursor, 0, NN * sizeof(int), stream);
  k_scatter<<<NE / 256, 256, 0, stream>>>(src, dst, rowptr, cursor, csr);
  k_gstart<<<1, 128, 0, stream>>>(batch, gstart);

  // weight transposes (bf16)
  k_wt<<<64, 512, 0, stream>>>(Wc1, Wt1);
  k_wt<<<64, 512, 0, stream>>>(Wc2, Wt2);
  k_wt<<<64, 512, 0, stream>>>(Wc3, Wt3);

  // embed -> bf16
  k_embed<<<NN / 4, 256, 0, stream>>>(x, W_emb, b_emb, g0, bt0, hba);

  const int LIN_GRID = NNP / 64;        // 782
  const int AGGR_GRID = (NN + 7) / 8;   // 6250
  // layer 1
  k_aggr<<<AGGR_GRID, 256, 0, stream>>>(hba, rowptr, csr, hmb);
  k_lin_mfma<1><<<LIN_GRID, 256, 0, stream>>>(hba, hmb, Wt1, bc1, g1, bt1, hbb);
  // layer 2
  k_aggr<<<AGGR_GRID, 256, 0, stream>>>(hbb, rowptr, csr, hmb);
  k_lin_mfma<1><<<LIN_GRID, 256, 0, stream>>>(hbb, hmb, Wt2, bc2, g2, bt2, hba);
  // layer 3
  k_aggr<<<AGGR_GRID, 256, 0, stream>>>(hba, rowptr, csr, hmb);
  k_lin_mfma<0><<<LIN_GRID, 256, 0, stream>>>(hba, hmb, Wt3, bc3, g3, bt3, out_node);

  // pooling
  k_pool1<<<NG * PSEG, 128, 0, stream>>>(out_node, gstart, ppart);
  k_pool2<<<NG, 256, 0, stream>>>(ppart, gstart, out_graph);
}

// Round 4
// 351.971 us; speedup vs baseline: 2.8941x; 1.5855x over previous
//
#include <hip/hip_runtime.h>
#include <hip/hip_bf16.h>
#include <math.h>

#define NN 50000
#define NNP 50048          // padded rows (782 blocks * 64)
#define NE 1600000
#define FIN 9
#define DD 128
#define NG 64
#define PSEG 16
#define LN_EPS 1e-5f

// binning: 196 buckets x 256 dst nodes
#define NB 196
#define BSHIFT 8
#define CH 8192            // edges per bscatter block
#define MAXBE 12288        // max entries per bucket (mean 8163, +46 sigma)

typedef __attribute__((ext_vector_type(8))) short bf16x8;
typedef __attribute__((ext_vector_type(4))) float f32x4;

static __device__ __forceinline__ float b2f(unsigned short u) {
  return __uint_as_float(((unsigned)u) << 16);
}
static __device__ __forceinline__ unsigned short f2b(float f) {
  __hip_bfloat16 h = __float2bfloat16(f);
  return __builtin_bit_cast(unsigned short, h);
}

// ---------------------------------------------------------------- bucket histogram
__global__ __launch_bounds__(256) void k_bhist(const int* __restrict__ dst,
                                               int* __restrict__ bcnt) {
  __shared__ int lh[NB];
  for (int i = threadIdx.x; i < NB; i += 256) lh[i] = 0;
  __syncthreads();
  for (int e = blockIdx.x * 256 + threadIdx.x; e < NE; e += gridDim.x * 256) {
    int d = dst[e];
    atomicAdd(&lh[d >> BSHIFT], 1);
  }
  __syncthreads();
  for (int i = threadIdx.x; i < NB; i += 256)
    if (lh[i]) atomicAdd(&bcnt[i], lh[i]);
}

// ---------------------------------------------------------------- bucket scan (1 block)
__global__ __launch_bounds__(256) void k_bscan(const int* __restrict__ bcnt,
                                               int* __restrict__ bbase,
                                               int* __restrict__ bcur) {
  __shared__ int tmp[256];
  const int t = threadIdx.x;
  tmp[t] = (t < NB) ? bcnt[t] : 0;
  __syncthreads();
  for (int off = 1; off < 256; off <<= 1) {
    int v = (t >= off) ? tmp[t - off] : 0;
    __syncthreads();
    tmp[t] += v;
    __syncthreads();
  }
  if (t < NB) {
    int excl = (t == 0) ? 0 : tmp[t - 1];
    bbase[t] = excl;
    bcur[t] = excl;
    if (t == NB - 1) bbase[NB] = tmp[t];
  }
}

// ---------------------------------------------------------------- binned scatter
// each block: load CH edges, LDS-sort by bucket, write each bucket run contiguously
__global__ __launch_bounds__(512) void k_bscatter(const int* __restrict__ src,
                                                  const int* __restrict__ dst,
                                                  int* __restrict__ bcur,
                                                  unsigned int* __restrict__ bents) {
  __shared__ int lh[NB], lbase[NB], gbase[NB], lcnt[NB];
  __shared__ int stmp[256];
  __shared__ unsigned int sbuf[CH];
  const int t = threadIdx.x;
  const int e0 = blockIdx.x * CH;
  const int n = min(CH, NE - e0);

  for (int i = t; i < NB; i += 512) { lh[i] = 0; lcnt[i] = 0; }
  __syncthreads();

  unsigned int ent[16];
  int eb[16];
#pragma unroll
  for (int k = 0; k < 16; ++k) {
    int i = k * 512 + t;
    if (i < n) {
      int s = src[e0 + i], d = dst[e0 + i];
      ent[k] = ((unsigned)d << 16) | (unsigned)s;  // both < 65536
      eb[k] = d >> BSHIFT;
      atomicAdd(&lh[eb[k]], 1);
    } else {
      eb[k] = -1;
    }
  }
  __syncthreads();
  // scan lh -> exclusive lbase
  if (t < 256) stmp[t] = (t < NB) ? lh[t] : 0;
  __syncthreads();
  for (int off = 1; off < 256; off <<= 1) {
    int v = 0;
    if (t < 256 && t >= off) v = stmp[t - off];
    __syncthreads();
    if (t < 256) stmp[t] += v;
    __syncthreads();
  }
  if (t < NB) lbase[t] = (t == 0) ? 0 : stmp[t - 1];
  __syncthreads();
  if (t < NB && lh[t] > 0) gbase[t] = atomicAdd(&bcur[t], lh[t]);
  __syncthreads();
#pragma unroll
  for (int k = 0; k < 16; ++k) {
    if (eb[k] >= 0) {
      int r = atomicAdd(&lcnt[eb[k]], 1);
      sbuf[lbase[eb[k]] + r] = ent[k];
    }
  }
  __syncthreads();
  for (int i = t; i < n; i += 512) {
    unsigned int e = sbuf[i];
    int b = e >> 24;  // (dst>>8)
    bents[gbase[b] + (i - lbase[b])] = e;
  }
}

// ---------------------------------------------------------------- per-bucket counting sort
// one block per bucket: sort entries by local dst, emit rowptr + ushort csr
__global__ __launch_bounds__(512) void k_sort(const unsigned int* __restrict__ bents,
                                              const int* __restrict__ bbase,
                                              int* __restrict__ rowptr,
                                              unsigned short* __restrict__ csr16) {
  __shared__ int lh[256], lsc[256], lc2[256];
  __shared__ unsigned short lsrc[MAXBE];
  const int b = blockIdx.x, t = threadIdx.x;
  const int base = bbase[b];
  const int nb = min(bbase[b + 1] - base, MAXBE);

  if (t < 256) { lh[t] = 0; lc2[t] = 0; }
  __syncthreads();
  for (int i = t; i < nb; i += 512) {
    unsigned int e = bents[base + i];
    atomicAdd(&lh[(e >> 16) & 255], 1);
  }
  __syncthreads();
  if (t < 256) lsc[t] = lh[t];
  __syncthreads();
  for (int off = 1; off < 256; off <<= 1) {
    int v = 0;
    if (t < 256 && t >= off) v = lsc[t - off];
    __syncthreads();
    if (t < 256) lsc[t] += v;
    __syncthreads();
  }
  int excl = 0;
  if (t < 256) excl = (t == 0) ? 0 : lsc[t - 1];
  __syncthreads();
  if (t < 256) {
    lsc[t] = excl;
    int gnode = b * 256 + t;
    if (gnode < NN) rowptr[gnode] = base + excl;
  }
  if (b == 0 && t == 0) rowptr[NN] = NE;
  __syncthreads();
  for (int i = t; i < nb; i += 512) {
    unsigned int e = bents[base + i];
    int dl = (e >> 16) & 255;
    int r = atomicAdd(&lc2[dl], 1);
    lsrc[lsc[dl] + r] = (unsigned short)(e & 0xFFFF);
  }
  __syncthreads();
  for (int i = t; i < nb; i += 512) csr16[base + i] = lsrc[i];
}

// ---------------------------------------------------------------- graph starts
__global__ __launch_bounds__(128) void k_gstart(const int* __restrict__ batch,
                                                int* __restrict__ gstart) {
  int g = threadIdx.x;
  if (g > NG) return;
  int lo = 0, hi = NN;
  while (lo < hi) {
    int mid = (lo + hi) >> 1;
    if (batch[mid] < g) lo = mid + 1; else hi = mid;
  }
  gstart[g] = lo;
}

// ---------------------------------------------------------------- W^T bf16 (Wt[n][k] = W[k][n])
__global__ __launch_bounds__(512) void k_wt(const float* __restrict__ W,
                                            unsigned short* __restrict__ Wt) {
  int idx = blockIdx.x * 512 + threadIdx.x;  // 0..32767
  int k = idx >> 7;
  int n = idx & 127;
  Wt[n * 256 + k] = f2b(W[k * DD + n]);
}

// ---------------------------------------------------------------- embed: relu(LN(x@W+b)) -> bf16
__global__ __launch_bounds__(256) void k_embed(const float* __restrict__ x,
                                               const float* __restrict__ W,
                                               const float* __restrict__ b,
                                               const float* __restrict__ gamma,
                                               const float* __restrict__ beta,
                                               unsigned short* __restrict__ hout) {
  const int wid = threadIdx.x >> 6;
  const int lane = threadIdx.x & 63;
  const int node = blockIdx.x * 4 + wid;
  if (node >= NN) return;
  float xr[FIN];
#pragma unroll
  for (int k = 0; k < FIN; ++k) xr[k] = x[node * FIN + k];
  const int c0 = lane, c1 = lane + 64;
  float a0 = b[c0], a1 = b[c1];
#pragma unroll
  for (int k = 0; k < FIN; ++k) {
    a0 += xr[k] * W[k * DD + c0];
    a1 += xr[k] * W[k * DD + c1];
  }
  float s = a0 + a1;
#pragma unroll
  for (int m = 1; m < 64; m <<= 1) s += __shfl_xor(s, m, 64);
  float mean = s * (1.f / DD);
  float d0 = a0 - mean, d1 = a1 - mean;
  float v = d0 * d0 + d1 * d1;
#pragma unroll
  for (int m = 1; m < 64; m <<= 1) v += __shfl_xor(v, m, 64);
  float r = rsqrtf(v * (1.f / DD) + LN_EPS);
  hout[(size_t)node * DD + c0] = f2b(fmaxf(d0 * r * gamma[c0] + beta[c0], 0.f));
  hout[(size_t)node * DD + c1] = f2b(fmaxf(d1 * r * gamma[c1] + beta[c1], 0.f));
}

// ---------------------------------------------------------------- scatter-mean (bf16 gather)
__global__ __launch_bounds__(256) void k_aggr(const unsigned short* __restrict__ hb,
                                              const int* __restrict__ rowptr,
                                              const unsigned short* __restrict__ csr16,
                                              unsigned short* __restrict__ hmb) {
  const int half = threadIdx.x >> 5;
  const int lane = threadIdx.x & 31;
  const int node = blockIdx.x * 8 + half;
  if (node >= NN) return;
  const int beg = rowptr[node], end = rowptr[node + 1];
  const ushort4* __restrict__ h4 = reinterpret_cast<const ushort4*>(hb);
  float ax = 0.f, ay = 0.f, az = 0.f, aw = 0.f;
  for (int base = beg; base < end; base += 32) {
    int m = min(32, end - base);
    int myidx = (lane < m) ? (int)csr16[base + lane] : 0;
    int j = 0;
    for (; j + 4 <= m; j += 4) {
      int s0 = __shfl(myidx, j + 0, 32);
      int s1 = __shfl(myidx, j + 1, 32);
      int s2 = __shfl(myidx, j + 2, 32);
      int s3 = __shfl(myidx, j + 3, 32);
      ushort4 v0 = h4[(size_t)s0 * 32 + lane];
      ushort4 v1 = h4[(size_t)s1 * 32 + lane];
      ushort4 v2 = h4[(size_t)s2 * 32 + lane];
      ushort4 v3 = h4[(size_t)s3 * 32 + lane];
      ax += b2f(v0.x) + b2f(v1.x) + b2f(v2.x) + b2f(v3.x);
      ay += b2f(v0.y) + b2f(v1.y) + b2f(v2.y) + b2f(v3.y);
      az += b2f(v0.z) + b2f(v1.z) + b2f(v2.z) + b2f(v3.z);
      aw += b2f(v0.w) + b2f(v1.w) + b2f(v2.w) + b2f(v3.w);
    }
    for (; j < m; ++j) {
      int s0 = __shfl(myidx, j, 32);
      ushort4 v = h4[(size_t)s0 * 32 + lane];
      ax += b2f(v.x); ay += b2f(v.y); az += b2f(v.z); aw += b2f(v.w);
    }
  }
  float inv = 1.f / (float)max(end - beg, 1);
  ushort4 o;
  o.x = f2b(ax * inv); o.y = f2b(ay * inv); o.z = f2b(az * inv); o.w = f2b(aw * inv);
  reinterpret_cast<ushort4*>(hmb)[(size_t)node * 32 + lane] = o;
}

// ---------------------------------------------------------------- MFMA linear(256->128)+LN+ReLU
template <int OUT_BF16>
__global__ __launch_bounds__(256) void k_lin_mfma(const unsigned short* __restrict__ hb,
                                                  const unsigned short* __restrict__ hmb,
                                                  const unsigned short* __restrict__ Wt,
                                                  const float* __restrict__ bias,
                                                  const float* __restrict__ gamma,
                                                  const float* __restrict__ beta,
                                                  void* __restrict__ outv) {
  const int tid = threadIdx.x;
  const int w = tid >> 6;
  const int l = tid & 63;
  const int c16 = l & 15;
  const int kg = l >> 4;
  const int rowBase = blockIdx.x * 64 + w * 16;

  f32x4 acc[8];
#pragma unroll
  for (int t = 0; t < 8; ++t) acc[t] = (f32x4){0.f, 0.f, 0.f, 0.f};

  const unsigned short* arow_self = hb + (size_t)(rowBase + c16) * DD;
  const unsigned short* arow_mean = hmb + (size_t)(rowBase + c16) * DD;

#pragma unroll
  for (int kc = 0; kc < 8; ++kc) {
    const unsigned short* arow = (kc < 4) ? arow_self : arow_mean;
    bf16x8 a = *reinterpret_cast<const bf16x8*>(arow + (kc & 3) * 32 + kg * 8);
#pragma unroll
    for (int t = 0; t < 8; ++t) {
      bf16x8 b = *reinterpret_cast<const bf16x8*>(
          Wt + (size_t)(t * 16 + c16) * 256 + kc * 32 + kg * 8);
      acc[t] = __builtin_amdgcn_mfma_f32_16x16x32_bf16(a, b, acc[t], 0, 0, 0);
    }
  }

  float bv[8], gv[8], btv[8];
#pragma unroll
  for (int t = 0; t < 8; ++t) {
    int c = t * 16 + c16;
    bv[t] = bias[c]; gv[t] = gamma[c]; btv[t] = beta[c];
  }
#pragma unroll
  for (int t = 0; t < 8; ++t)
#pragma unroll
    for (int i = 0; i < 4; ++i) acc[t][i] += bv[t];

#pragma unroll
  for (int i = 0; i < 4; ++i) {
    float s = 0.f;
#pragma unroll
    for (int t = 0; t < 8; ++t) s += acc[t][i];
#pragma unroll
    for (int m = 1; m < 16; m <<= 1) s += __shfl_xor(s, m, 64);
    float mean = s * (1.f / DD);
    float v = 0.f;
#pragma unroll
    for (int t = 0; t < 8; ++t) {
      float d = acc[t][i] - mean;
      v += d * d;
    }
#pragma unroll
    for (int m = 1; m < 16; m <<= 1) v += __shfl_xor(v, m, 64);
    float r = rsqrtf(v * (1.f / DD) + LN_EPS);
    int onode = rowBase + kg * 4 + i;
    if (onode < NN) {
#pragma unroll
      for (int t = 0; t < 8; ++t) {
        float val = fmaxf((acc[t][i] - mean) * r * gv[t] + btv[t], 0.f);
        int c = t * 16 + c16;
        if (OUT_BF16) {
          ((unsigned short*)outv)[(size_t)onode * DD + c] = f2b(val);
        } else {
          ((float*)outv)[(size_t)onode * DD + c] = val;
        }
      }
    }
  }
}

// ---------------------------------------------------------------- graph pooling (mean+max)
__global__ __launch_bounds__(128) void k_pool1(const float* __restrict__ ne,
                                               const int* __restrict__ gstart,
                                               float* __restrict__ part) {
  const int g = blockIdx.x / PSEG;
  const int sg = blockIdx.x % PSEG;
  const int c = threadIdx.x;
  const int beg = gstart[g], end = gstart[g + 1];
  const int len = end - beg;
  const int per = (len + PSEG - 1) / PSEG;
  const int n0 = beg + sg * per;
  const int n1 = min(n0 + per, end);
  float s = 0.f, mx = -INFINITY;
  for (int n = n0; n < n1; ++n) {
    float v = ne[(size_t)n * DD + c];
    s += v;
    mx = fmaxf(mx, v);
  }
  part[(size_t)(g * PSEG + sg) * 256 + c] = s;
  part[(size_t)(g * PSEG + sg) * 256 + 128 + c] = mx;
}

__global__ __launch_bounds__(256) void k_pool2(const float* __restrict__ part,
                                               const int* __restrict__ gstart,
                                               float* __restrict__ gout) {
  const int g = blockIdx.x;
  const int c = threadIdx.x;
  const bool isMax = c >= 128;
  float acc = isMax ? -INFINITY : 0.f;
  for (int sg = 0; sg < PSEG; ++sg) {
    float v = part[(size_t)(g * PSEG + sg) * 256 + c];
    acc = isMax ? fmaxf(acc, v) : (acc + v);
  }
  if (!isMax) acc /= (float)max(gstart[g + 1] - gstart[g], 1);
  gout[(size_t)g * 256 + c] = acc;
}

// ---------------------------------------------------------------- launch
static inline size_t align_up(size_t v, size_t a) { return (v + a - 1) & ~(a - 1); }

extern "C" void kernel_launch(void* const* d_in, const int* in_sizes, int n_in,
                              void* d_out, int out_size, void* d_ws, size_t ws_size,
                              hipStream_t stream) {
  const float* x     = (const float*)d_in[0];
  const int*   ei    = (const int*)d_in[1];
  const int*   batch = (const int*)d_in[2];
  const float* W_emb = (const float*)d_in[3];
  const float* b_emb = (const float*)d_in[4];
  const float* g0    = (const float*)d_in[5];
  const float* bt0   = (const float*)d_in[6];
  const float* Wc1   = (const float*)d_in[7];
  const float* bc1   = (const float*)d_in[8];
  const float* g1    = (const float*)d_in[9];
  const float* bt1   = (const float*)d_in[10];
  const float* Wc2   = (const float*)d_in[11];
  const float* bc2   = (const float*)d_in[12];
  const float* g2    = (const float*)d_in[13];
  const float* bt2   = (const float*)d_in[14];
  const float* Wc3   = (const float*)d_in[15];
  const float* bc3   = (const float*)d_in[16];
  const float* g3    = (const float*)d_in[17];
  const float* bt3   = (const float*)d_in[18];

  const int* src = ei;
  const int* dst = ei + NE;

  float* out_node  = (float*)d_out;                     // N*D fp32
  float* out_graph = (float*)d_out + (size_t)NN * DD;   // G*256 fp32

  char* p = (char*)d_ws;
  auto alloc = [&](size_t bytes) { char* r = p; p += align_up(bytes, 256); return r; };
  int*            rowptr = (int*)alloc((NN + 1) * sizeof(int));
  int*            bcnt   = (int*)alloc(NB * sizeof(int));
  int*            bbase  = (int*)alloc((NB + 1) * sizeof(int));
  int*            bcur   = (int*)alloc(NB * sizeof(int));
  int*            gstart = (int*)alloc((NG + 1) * sizeof(int));
  unsigned int*   bents  = (unsigned int*)alloc((size_t)NE * 4);
  unsigned short* csr16  = (unsigned short*)alloc((size_t)NE * 2);
  unsigned short* hba    = (unsigned short*)alloc((size_t)NNP * DD * 2);
  unsigned short* hbb    = (unsigned short*)alloc((size_t)NNP * DD * 2);
  unsigned short* hmb    = (unsigned short*)alloc((size_t)NNP * DD * 2);
  unsigned short* Wt1    = (unsigned short*)alloc(128 * 256 * 2);
  unsigned short* Wt2    = (unsigned short*)alloc(128 * 256 * 2);
  unsigned short* Wt3    = (unsigned short*)alloc(128 * 256 * 2);
  float*          ppart  = (float*)alloc((size_t)NG * PSEG * 256 * sizeof(float));

  // zero pad rows so MFMA pad lanes never see garbage
  const size_t padB = (size_t)(NNP - NN) * DD * 2;
  hipMemsetAsync(hba + (size_t)NN * DD, 0, padB, stream);
  hipMemsetAsync(hbb + (size_t)NN * DD, 0, padB, stream);
  hipMemsetAsync(hmb + (size_t)NN * DD, 0, padB, stream);

  // CSR build via binned counting sort (reused by all 3 layers)
  hipMemsetAsync(bcnt, 0, NB * sizeof(int), stream);
  k_bhist<<<256, 256, 0, stream>>>(dst, bcnt);
  k_bscan<<<1, 256, 0, stream>>>(bcnt, bbase, bcur);
  k_bscatter<<<(NE + CH - 1) / CH, 512, 0, stream>>>(src, dst, bcur, bents);
  k_sort<<<NB, 512, 0, stream>>>(bents, bbase, rowptr, csr16);
  k_gstart<<<1, 128, 0, stream>>>(batch, gstart);

  // weight transposes (bf16)
  k_wt<<<64, 512, 0, stream>>>(Wc1, Wt1);
  k_wt<<<64, 512, 0, stream>>>(Wc2, Wt2);
  k_wt<<<64, 512, 0, stream>>>(Wc3, Wt3);

  // embed -> bf16
  k_embed<<<NN / 4, 256, 0, stream>>>(x, W_emb, b_emb, g0, bt0, hba);

  const int LIN_GRID = NNP / 64;        // 782
  const int AGGR_GRID = (NN + 7) / 8;   // 6250
  // layer 1
  k_aggr<<<AGGR_GRID, 256, 0, stream>>>(hba, rowptr, csr16, hmb);
  k_lin_mfma<1><<<LIN_GRID, 256, 0, stream>>>(hba, hmb, Wt1, bc1, g1, bt1, hbb);
  // layer 2
  k_aggr<<<AGGR_GRID, 256, 0, stream>>>(hbb, rowptr, csr16, hmb);
  k_lin_mfma<1><<<LIN_GRID, 256, 0, stream>>>(hbb, hmb, Wt2, bc2, g2, bt2, hba);
  // layer 3
  k_aggr<<<AGGR_GRID, 256, 0, stream>>>(hba, rowptr, csr16, hmb);
  k_lin_mfma<0><<<LIN_GRID, 256, 0, stream>>>(hba, hmb, Wt3, bc3, g3, bt3, out_node);

  // pooling
  k_pool1<<<NG * PSEG, 128, 0, stream>>>(out_node, gstart, ppart);
  k_pool2<<<NG, 256, 0, stream>>>(ppart, gstart, out_graph);
}

// Round 5
// 349.886 us; speedup vs baseline: 2.9114x; 1.0060x over previous
//
#include <hip/hip_runtime.h>
#include <hip/hip_bf16.h>
#include <math.h>

#define NN 50000
#define NNP 50048          // padded rows (782 blocks * 64)
#define NE 1600000
#define FIN 9
#define DD 128
#define NG 64
#define PSEG 16
#define LN_EPS 1e-5f

// binning: 196 buckets x 256 dst nodes
#define NB 196
#define BSHIFT 8
#define CH 8192            // edges per bscatter block
#define MAXPB 20480        // padded entries reserved per bucket (worst <= ~16.6K)

typedef __attribute__((ext_vector_type(8))) short bf16x8;
typedef __attribute__((ext_vector_type(4))) float f32x4;

static __device__ __forceinline__ float b2f(unsigned short u) {
  return __uint_as_float(((unsigned)u) << 16);
}
static __device__ __forceinline__ unsigned short f2b(float f) {
  __hip_bfloat16 h = __float2bfloat16(f);
  return __builtin_bit_cast(unsigned short, h);
}

// ---------------------------------------------------------------- bucket histogram
__global__ __launch_bounds__(256) void k_bhist(const int* __restrict__ dst,
                                               int* __restrict__ bcnt) {
  __shared__ int lh[NB];
  for (int i = threadIdx.x; i < NB; i += 256) lh[i] = 0;
  __syncthreads();
  for (int e = blockIdx.x * 256 + threadIdx.x; e < NE; e += gridDim.x * 256) {
    int d = dst[e];
    atomicAdd(&lh[d >> BSHIFT], 1);
  }
  __syncthreads();
  for (int i = threadIdx.x; i < NB; i += 256)
    if (lh[i]) atomicAdd(&bcnt[i], lh[i]);
}

// ---------------------------------------------------------------- bucket scan (1 block)
__global__ __launch_bounds__(256) void k_bscan(const int* __restrict__ bcnt,
                                               int* __restrict__ bbase,
                                               int* __restrict__ bcur) {
  __shared__ int tmp[256];
  const int t = threadIdx.x;
  tmp[t] = (t < NB) ? bcnt[t] : 0;
  __syncthreads();
  for (int off = 1; off < 256; off <<= 1) {
    int v = (t >= off) ? tmp[t - off] : 0;
    __syncthreads();
    tmp[t] += v;
    __syncthreads();
  }
  if (t < NB) {
    int excl = (t == 0) ? 0 : tmp[t - 1];
    bbase[t] = excl;
    bcur[t] = excl;
    if (t == NB - 1) bbase[NB] = tmp[t];
  }
}

// ---------------------------------------------------------------- binned scatter
__global__ __launch_bounds__(512) void k_bscatter(const int* __restrict__ src,
                                                  const int* __restrict__ dst,
                                                  int* __restrict__ bcur,
                                                  unsigned int* __restrict__ bents) {
  __shared__ int lh[NB], lbase[NB], gbase[NB], lcnt[NB];
  __shared__ int stmp[256];
  __shared__ unsigned int sbuf[CH];
  const int t = threadIdx.x;
  const int e0 = blockIdx.x * CH;
  const int n = min(CH, NE - e0);

  for (int i = t; i < NB; i += 512) { lh[i] = 0; lcnt[i] = 0; }
  __syncthreads();

  unsigned int ent[16];
  int eb[16];
#pragma unroll
  for (int k = 0; k < 16; ++k) {
    int i = k * 512 + t;
    if (i < n) {
      int s = src[e0 + i], d = dst[e0 + i];
      ent[k] = ((unsigned)d << 16) | (unsigned)s;  // both < 65536
      eb[k] = d >> BSHIFT;
      atomicAdd(&lh[eb[k]], 1);
    } else {
      eb[k] = -1;
    }
  }
  __syncthreads();
  if (t < 256) stmp[t] = (t < NB) ? lh[t] : 0;
  __syncthreads();
  for (int off = 1; off < 256; off <<= 1) {
    int v = 0;
    if (t < 256 && t >= off) v = stmp[t - off];
    __syncthreads();
    if (t < 256) stmp[t] += v;
    __syncthreads();
  }
  if (t < NB) lbase[t] = (t == 0) ? 0 : stmp[t - 1];
  __syncthreads();
  if (t < NB && lh[t] > 0) gbase[t] = atomicAdd(&bcur[t], lh[t]);
  __syncthreads();
#pragma unroll
  for (int k = 0; k < 16; ++k) {
    if (eb[k] >= 0) {
      int r = atomicAdd(&lcnt[eb[k]], 1);
      sbuf[lbase[eb[k]] + r] = ent[k];
    }
  }
  __syncthreads();
  for (int i = t; i < n; i += 512) {
    unsigned int e = sbuf[i];
    int b = e >> 24;
    bents[gbase[b] + (i - lbase[b])] = e;
  }
}

// ---------------------------------------------------------------- per-bucket counting sort
// emits PADDED csr (each node's run padded to x32 with index NN), padded rowptr, true degree
__global__ __launch_bounds__(512) void k_sort(const unsigned int* __restrict__ bents,
                                              const int* __restrict__ bbase,
                                              int* __restrict__ prowptr,
                                              int* __restrict__ degv,
                                              unsigned short* __restrict__ csr16) {
  __shared__ int lh[256], lsc[256], plsc[256], lc2[256];
  const int b = blockIdx.x, t = threadIdx.x;
  const int base = bbase[b];
  const int nb = bbase[b + 1] - base;
  const int pbase = b * MAXPB;

  if (t < 256) { lh[t] = 0; lc2[t] = 0; }
  __syncthreads();
  for (int i = t; i < nb; i += 512)
    atomicAdd(&lh[(bents[base + i] >> 16) & 255], 1);
  __syncthreads();
  if (t < 256) { lsc[t] = lh[t]; plsc[t] = (lh[t] + 31) & ~31; }
  __syncthreads();
  for (int off = 1; off < 256; off <<= 1) {
    int v = 0, pv = 0;
    if (t < 256 && t >= off) { v = lsc[t - off]; pv = plsc[t - off]; }
    __syncthreads();
    if (t < 256) { lsc[t] += v; plsc[t] += pv; }
    __syncthreads();
  }
  int ex = 0, pex = 0;
  if (t < 256) { ex = (t == 0) ? 0 : lsc[t - 1]; pex = (t == 0) ? 0 : plsc[t - 1]; }
  __syncthreads();
  if (t < 256) {
    lsc[t] = ex;
    plsc[t] = pex;
    int gnode = b * 256 + t;
    if (gnode < NN) { prowptr[gnode] = pbase + pex; degv[gnode] = lh[t]; }
  }
  __syncthreads();
  for (int i = t; i < nb; i += 512) {
    unsigned int e = bents[base + i];
    int dl = (e >> 16) & 255;
    int r = atomicAdd(&lc2[dl], 1);
    csr16[pbase + plsc[dl] + r] = (unsigned short)(e & 0xFFFF);
  }
  __syncthreads();
  if (t < 256) {
    int d = lh[t];
    int pd = (d + 31) & ~31;
    int o = pbase + plsc[t];
    for (int k = d; k < pd; ++k) csr16[o + k] = (unsigned short)NN;  // zero row
  }
}

// ---------------------------------------------------------------- graph starts
__global__ __launch_bounds__(128) void k_gstart(const int* __restrict__ batch,
                                                int* __restrict__ gstart) {
  int g = threadIdx.x;
  if (g > NG) return;
  int lo = 0, hi = NN;
  while (lo < hi) {
    int mid = (lo + hi) >> 1;
    if (batch[mid] < g) lo = mid + 1; else hi = mid;
  }
  gstart[g] = lo;
}

// ---------------------------------------------------------------- W^T bf16
__global__ __launch_bounds__(512) void k_wt(const float* __restrict__ W,
                                            unsigned short* __restrict__ Wt) {
  int idx = blockIdx.x * 512 + threadIdx.x;
  int k = idx >> 7;
  int n = idx & 127;
  Wt[n * 256 + k] = f2b(W[k * DD + n]);
}

// ---------------------------------------------------------------- embed
__global__ __launch_bounds__(256) void k_embed(const float* __restrict__ x,
                                               const float* __restrict__ W,
                                               const float* __restrict__ b,
                                               const float* __restrict__ gamma,
                                               const float* __restrict__ beta,
                                               unsigned short* __restrict__ hout) {
  const int wid = threadIdx.x >> 6;
  const int lane = threadIdx.x & 63;
  const int node = blockIdx.x * 4 + wid;
  if (node >= NN) return;
  float xr[FIN];
#pragma unroll
  for (int k = 0; k < FIN; ++k) xr[k] = x[node * FIN + k];
  const int c0 = lane, c1 = lane + 64;
  float a0 = b[c0], a1 = b[c1];
#pragma unroll
  for (int k = 0; k < FIN; ++k) {
    a0 += xr[k] * W[k * DD + c0];
    a1 += xr[k] * W[k * DD + c1];
  }
  float s = a0 + a1;
#pragma unroll
  for (int m = 1; m < 64; m <<= 1) s += __shfl_xor(s, m, 64);
  float mean = s * (1.f / DD);
  float d0 = a0 - mean, d1 = a1 - mean;
  float v = d0 * d0 + d1 * d1;
#pragma unroll
  for (int m = 1; m < 64; m <<= 1) v += __shfl_xor(v, m, 64);
  float r = rsqrtf(v * (1.f / DD) + LN_EPS);
  hout[(size_t)node * DD + c0] = f2b(fmaxf(d0 * r * gamma[c0] + beta[c0], 0.f));
  hout[(size_t)node * DD + c1] = f2b(fmaxf(d1 * r * gamma[c1] + beta[c1], 0.f));
}

// ---------------------------------------------------------------- scatter-mean
// one WAVE per node; scalar (SGPR) neighbor indices; saddr gathers; padded chunks of 32
__global__ __launch_bounds__(256) void k_aggr(const unsigned short* __restrict__ hb,
                                              const int* __restrict__ prowptr,
                                              const int* __restrict__ degv,
                                              const unsigned short* __restrict__ csr16,
                                              unsigned short* __restrict__ hmb) {
  const int wid = __builtin_amdgcn_readfirstlane(threadIdx.x >> 6);
  const int lane = threadIdx.x & 63;
  const int node = blockIdx.x * 4 + wid;   // grid covers exactly NN
  const int pbeg = __builtin_amdgcn_readfirstlane(prowptr[node]);
  const int deg = __builtin_amdgcn_readfirstlane(degv[node]);
  const int nch = (deg + 31) >> 5;

  const unsigned int* __restrict__ cp =
      reinterpret_cast<const unsigned int*>(csr16 + pbeg);  // 64B-aligned, uniform
  float alo = 0.f, ahi = 0.f;
  for (int c = 0; c < nch; ++c) {
#pragma unroll
    for (int q = 0; q < 16; ++q) {
      unsigned int pair = cp[c * 16 + q];                   // scalar load
      const unsigned int* r0 =
          reinterpret_cast<const unsigned int*>(hb + (size_t)(pair & 0xFFFFu) * DD);
      const unsigned int* r1 =
          reinterpret_cast<const unsigned int*>(hb + (size_t)(pair >> 16) * DD);
      unsigned int u0 = r0[lane];                           // saddr + lane*4
      unsigned int u1 = r1[lane];
      alo += __uint_as_float(u0 << 16);
      ahi += __uint_as_float(u0 & 0xFFFF0000u);
      alo += __uint_as_float(u1 << 16);
      ahi += __uint_as_float(u1 & 0xFFFF0000u);
    }
  }
  float inv = 1.f / (float)max(deg, 1);
  unsigned int o = ((unsigned int)f2b(ahi * inv) << 16) | (unsigned int)f2b(alo * inv);
  reinterpret_cast<unsigned int*>(hmb)[(size_t)node * 64 + lane] = o;
}

// ---------------------------------------------------------------- MFMA linear(256->128)+LN+ReLU
template <int OUT_BF16>
__global__ __launch_bounds__(256) void k_lin_mfma(const unsigned short* __restrict__ hb,
                                                  const unsigned short* __restrict__ hmb,
                                                  const unsigned short* __restrict__ Wt,
                                                  const float* __restrict__ bias,
                                                  const float* __restrict__ gamma,
                                                  const float* __restrict__ beta,
                                                  void* __restrict__ outv) {
  const int tid = threadIdx.x;
  const int w = tid >> 6;
  const int l = tid & 63;
  const int c16 = l & 15;
  const int kg = l >> 4;
  const int rowBase = blockIdx.x * 64 + w * 16;

  f32x4 acc[8];
#pragma unroll
  for (int t = 0; t < 8; ++t) acc[t] = (f32x4){0.f, 0.f, 0.f, 0.f};

  const unsigned short* arow_self = hb + (size_t)(rowBase + c16) * DD;
  const unsigned short* arow_mean = hmb + (size_t)(rowBase + c16) * DD;

#pragma unroll
  for (int kc = 0; kc < 8; ++kc) {
    const unsigned short* arow = (kc < 4) ? arow_self : arow_mean;
    bf16x8 a = *reinterpret_cast<const bf16x8*>(arow + (kc & 3) * 32 + kg * 8);
#pragma unroll
    for (int t = 0; t < 8; ++t) {
      bf16x8 b = *reinterpret_cast<const bf16x8*>(
          Wt + (size_t)(t * 16 + c16) * 256 + kc * 32 + kg * 8);
      acc[t] = __builtin_amdgcn_mfma_f32_16x16x32_bf16(a, b, acc[t], 0, 0, 0);
    }
  }

  float bv[8], gv[8], btv[8];
#pragma unroll
  for (int t = 0; t < 8; ++t) {
    int c = t * 16 + c16;
    bv[t] = bias[c]; gv[t] = gamma[c]; btv[t] = beta[c];
  }
#pragma unroll
  for (int t = 0; t < 8; ++t)
#pragma unroll
    for (int i = 0; i < 4; ++i) acc[t][i] += bv[t];

#pragma unroll
  for (int i = 0; i < 4; ++i) {
    float s = 0.f;
#pragma unroll
    for (int t = 0; t < 8; ++t) s += acc[t][i];
#pragma unroll
    for (int m = 1; m < 16; m <<= 1) s += __shfl_xor(s, m, 64);
    float mean = s * (1.f / DD);
    float v = 0.f;
#pragma unroll
    for (int t = 0; t < 8; ++t) {
      float d = acc[t][i] - mean;
      v += d * d;
    }
#pragma unroll
    for (int m = 1; m < 16; m <<= 1) v += __shfl_xor(v, m, 64);
    float r = rsqrtf(v * (1.f / DD) + LN_EPS);
    int onode = rowBase + kg * 4 + i;
    if (onode < NN) {
#pragma unroll
      for (int t = 0; t < 8; ++t) {
        float val = fmaxf((acc[t][i] - mean) * r * gv[t] + btv[t], 0.f);
        int c = t * 16 + c16;
        if (OUT_BF16) {
          ((unsigned short*)outv)[(size_t)onode * DD + c] = f2b(val);
        } else {
          ((float*)outv)[(size_t)onode * DD + c] = val;
        }
      }
    }
  }
}

// ---------------------------------------------------------------- graph pooling (mean+max)
__global__ __launch_bounds__(128) void k_pool1(const float* __restrict__ ne,
                                               const int* __restrict__ gstart,
                                               float* __restrict__ part) {
  const int g = blockIdx.x / PSEG;
  const int sg = blockIdx.x % PSEG;
  const int c = threadIdx.x;
  const int beg = gstart[g], end = gstart[g + 1];
  const int len = end - beg;
  const int per = (len + PSEG - 1) / PSEG;
  const int n0 = beg + sg * per;
  const int n1 = min(n0 + per, end);
  float s = 0.f, mx = -INFINITY;
  for (int n = n0; n < n1; ++n) {
    float v = ne[(size_t)n * DD + c];
    s += v;
    mx = fmaxf(mx, v);
  }
  part[(size_t)(g * PSEG + sg) * 256 + c] = s;
  part[(size_t)(g * PSEG + sg) * 256 + 128 + c] = mx;
}

__global__ __launch_bounds__(256) void k_pool2(const float* __restrict__ part,
                                               const int* __restrict__ gstart,
                                               float* __restrict__ gout) {
  const int g = blockIdx.x;
  const int c = threadIdx.x;
  const bool isMax = c >= 128;
  float acc = isMax ? -INFINITY : 0.f;
  for (int sg = 0; sg < PSEG; ++sg) {
    float v = part[(size_t)(g * PSEG + sg) * 256 + c];
    acc = isMax ? fmaxf(acc, v) : (acc + v);
  }
  if (!isMax) acc /= (float)max(gstart[g + 1] - gstart[g], 1);
  gout[(size_t)g * 256 + c] = acc;
}

// ---------------------------------------------------------------- launch
static inline size_t align_up(size_t v, size_t a) { return (v + a - 1) & ~(a - 1); }

extern "C" void kernel_launch(void* const* d_in, const int* in_sizes, int n_in,
                              void* d_out, int out_size, void* d_ws, size_t ws_size,
                              hipStream_t stream) {
  const float* x     = (const float*)d_in[0];
  const int*   ei    = (const int*)d_in[1];
  const int*   batch = (const int*)d_in[2];
  const float* W_emb = (const float*)d_in[3];
  const float* b_emb = (const float*)d_in[4];
  const float* g0    = (const float*)d_in[5];
  const float* bt0   = (const float*)d_in[6];
  const float* Wc1   = (const float*)d_in[7];
  const float* bc1   = (const float*)d_in[8];
  const float* g1    = (const float*)d_in[9];
  const float* bt1   = (const float*)d_in[10];
  const float* Wc2   = (const float*)d_in[11];
  const float* bc2   = (const float*)d_in[12];
  const float* g2    = (const float*)d_in[13];
  const float* bt2   = (const float*)d_in[14];
  const float* Wc3   = (const float*)d_in[15];
  const float* bc3   = (const float*)d_in[16];
  const float* g3    = (const float*)d_in[17];
  const float* bt3   = (const float*)d_in[18];

  const int* src = ei;
  const int* dst = ei + NE;

  float* out_node  = (float*)d_out;                     // N*D fp32
  float* out_graph = (float*)d_out + (size_t)NN * DD;   // G*256 fp32

  char* p = (char*)d_ws;
  auto alloc = [&](size_t bytes) { char* r = p; p += align_up(bytes, 256); return r; };
  int*            prowptr = (int*)alloc((size_t)NN * sizeof(int));
  int*            degv    = (int*)alloc((size_t)NN * sizeof(int));
  int*            bcnt    = (int*)alloc(NB * sizeof(int));
  int*            bbase   = (int*)alloc((NB + 1) * sizeof(int));
  int*            bcur    = (int*)alloc(NB * sizeof(int));
  int*            gstart  = (int*)alloc((NG + 1) * sizeof(int));
  unsigned int*   bents   = (unsigned int*)alloc((size_t)NE * 4);
  unsigned short* csr16   = (unsigned short*)alloc((size_t)NB * MAXPB * 2);
  unsigned short* hba     = (unsigned short*)alloc((size_t)NNP * DD * 2);
  unsigned short* hbb     = (unsigned short*)alloc((size_t)NNP * DD * 2);
  unsigned short* hmb     = (unsigned short*)alloc((size_t)NNP * DD * 2);
  unsigned short* Wt1     = (unsigned short*)alloc(128 * 256 * 2);
  unsigned short* Wt2     = (unsigned short*)alloc(128 * 256 * 2);
  unsigned short* Wt3     = (unsigned short*)alloc(128 * 256 * 2);
  float*          ppart   = (float*)alloc((size_t)NG * PSEG * 256 * sizeof(float));

  // zero pad rows so MFMA pad lanes / CSR pad gathers see zeros
  const size_t padB = (size_t)(NNP - NN) * DD * 2;
  hipMemsetAsync(hba + (size_t)NN * DD, 0, padB, stream);
  hipMemsetAsync(hbb + (size_t)NN * DD, 0, padB, stream);
  hipMemsetAsync(hmb + (size_t)NN * DD, 0, padB, stream);

  // CSR build via binned counting sort (padded, reused by all 3 layers)
  hipMemsetAsync(bcnt, 0, NB * sizeof(int), stream);
  k_bhist<<<256, 256, 0, stream>>>(dst, bcnt);
  k_bscan<<<1, 256, 0, stream>>>(bcnt, bbase, bcur);
  k_bscatter<<<(NE + CH - 1) / CH, 512, 0, stream>>>(src, dst, bcur, bents);
  k_sort<<<NB, 512, 0, stream>>>(bents, bbase, prowptr, degv, csr16);
  k_gstart<<<1, 128, 0, stream>>>(batch, gstart);

  // weight transposes (bf16)
  k_wt<<<64, 512, 0, stream>>>(Wc1, Wt1);
  k_wt<<<64, 512, 0, stream>>>(Wc2, Wt2);
  k_wt<<<64, 512, 0, stream>>>(Wc3, Wt3);

  // embed -> bf16
  k_embed<<<NN / 4, 256, 0, stream>>>(x, W_emb, b_emb, g0, bt0, hba);

  const int LIN_GRID = NNP / 64;   // 782
  const int AGGR_GRID = NN / 4;    // 12500 (wave per node)
  // layer 1
  k_aggr<<<AGGR_GRID, 256, 0, stream>>>(hba, prowptr, degv, csr16, hmb);
  k_lin_mfma<1><<<LIN_GRID, 256, 0, stream>>>(hba, hmb, Wt1, bc1, g1, bt1, hbb);
  // layer 2
  k_aggr<<<AGGR_GRID, 256, 0, stream>>>(hbb, prowptr, degv, csr16, hmb);
  k_lin_mfma<1><<<LIN_GRID, 256, 0, stream>>>(hbb, hmb, Wt2, bc2, g2, bt2, hba);
  // layer 3
  k_aggr<<<AGGR_GRID, 256, 0, stream>>>(hba, prowptr, degv, csr16, hmb);
  k_lin_mfma<0><<<LIN_GRID, 256, 0, stream>>>(hba, hmb, Wt3, bc3, g3, bt3, out_node);

  // pooling
  k_pool1<<<NG * PSEG, 128, 0, stream>>>(out_node, gstart, ppart);
  k_pool2<<<NG, 256, 0, stream>>>(ppart, gstart, out_graph);
}

// Round 6
// 317.036 us; speedup vs baseline: 3.2131x; 1.1036x over previous
//
#include <hip/hip_runtime.h>
#include <hip/hip_bf16.h>
#include <math.h>

#define NN 50000
#define NNP 50048          // padded rows (782 blocks * 64)
#define NE 1600000
#define FIN 9
#define DD 128
#define NG 64
#define PSEG 16
#define LN_EPS 1e-5f

// binning: 196 buckets x 256 dst nodes, fixed regions
#define NB 196
#define BSHIFT 8
#define CH 8192            // edges per bscatter block
#define MAXBE 12288        // raw entries reserved per bucket (mean 8163, +45 sigma)
#define MAXPB 20480        // padded csr entries reserved per bucket (max 12288+7936)

typedef __attribute__((ext_vector_type(8))) short bf16x8;
typedef __attribute__((ext_vector_type(4))) float f32x4;

static __device__ __forceinline__ unsigned short f2b(float f) {
  __hip_bfloat16 h = __float2bfloat16(f);
  return __builtin_bit_cast(unsigned short, h);
}

// ---------------------------------------------------------------- prep: Wt x3, bcur, gstart, pads
__global__ __launch_bounds__(256) void k_prep(const float* __restrict__ Wc1,
                                              const float* __restrict__ Wc2,
                                              const float* __restrict__ Wc3,
                                              unsigned short* __restrict__ Wt1,
                                              unsigned short* __restrict__ Wt2,
                                              unsigned short* __restrict__ Wt3,
                                              int* __restrict__ bcur,
                                              const int* __restrict__ batch,
                                              int* __restrict__ gstart,
                                              unsigned short* __restrict__ hba,
                                              unsigned short* __restrict__ hbb) {
  const int bid = blockIdx.x;
  const int t = threadIdx.x;
  if (bid < 384) {
    const float* W = (bid < 128) ? Wc1 : (bid < 256) ? Wc2 : Wc3;
    unsigned short* Wt = (bid < 128) ? Wt1 : (bid < 256) ? Wt2 : Wt3;
    int idx = (bid & 127) * 256 + t;  // 0..32767
    int k = idx >> 7;
    int n = idx & 127;
    Wt[n * 256 + k] = f2b(W[k * DD + n]);
  } else if (bid == 384) {
    if (t < NB) bcur[t] = t * MAXBE;
  } else if (bid == 385) {
    if (t <= NG) {
      int lo = 0, hi = NN;
      while (lo < hi) {
        int mid = (lo + hi) >> 1;
        if (batch[mid] < t) lo = mid + 1; else hi = mid;
      }
      gstart[t] = lo;
    }
  } else if (bid == 386) {
    unsigned int* p = reinterpret_cast<unsigned int*>(hba + (size_t)NN * DD);
    for (int i = t; i < (NNP - NN) * DD / 2; i += 256) p[i] = 0;
  } else {
    unsigned int* p = reinterpret_cast<unsigned int*>(hbb + (size_t)NN * DD);
    for (int i = t; i < (NNP - NN) * DD / 2; i += 256) p[i] = 0;
  }
}

// ---------------------------------------------------------------- binned scatter (fixed regions)
__global__ __launch_bounds__(512) void k_bscatter(const int* __restrict__ src,
                                                  const int* __restrict__ dst,
                                                  int* __restrict__ bcur,
                                                  unsigned int* __restrict__ bents) {
  __shared__ int lh[NB], lbase[NB], gbase[NB], lcnt[NB];
  __shared__ int stmp[256];
  __shared__ unsigned int sbuf[CH];
  const int t = threadIdx.x;
  const int e0 = blockIdx.x * CH;
  const int n = min(CH, NE - e0);

  for (int i = t; i < NB; i += 512) { lh[i] = 0; lcnt[i] = 0; }
  __syncthreads();

  unsigned int ent[16];
  int eb[16];
#pragma unroll
  for (int k = 0; k < 16; ++k) {
    int i = k * 512 + t;
    if (i < n) {
      int s = src[e0 + i], d = dst[e0 + i];
      ent[k] = ((unsigned)d << 16) | (unsigned)s;  // both < 65536
      eb[k] = d >> BSHIFT;
      atomicAdd(&lh[eb[k]], 1);
    } else {
      eb[k] = -1;
    }
  }
  __syncthreads();
  if (t < 256) stmp[t] = (t < NB) ? lh[t] : 0;
  __syncthreads();
  for (int off = 1; off < 256; off <<= 1) {
    int v = 0;
    if (t < 256 && t >= off) v = stmp[t - off];
    __syncthreads();
    if (t < 256) stmp[t] += v;
    __syncthreads();
  }
  if (t < NB) lbase[t] = (t == 0) ? 0 : stmp[t - 1];
  __syncthreads();
  if (t < NB && lh[t] > 0) gbase[t] = atomicAdd(&bcur[t], lh[t]);
  __syncthreads();
#pragma unroll
  for (int k = 0; k < 16; ++k) {
    if (eb[k] >= 0) {
      int r = atomicAdd(&lcnt[eb[k]], 1);
      sbuf[lbase[eb[k]] + r] = ent[k];
    }
  }
  __syncthreads();
  for (int i = t; i < n; i += 512) {
    unsigned int e = sbuf[i];
    int b = e >> 24;
    int pos = gbase[b] + (i - lbase[b]);
    if (pos < (b + 1) * MAXBE) bents[pos] = e;  // overflow guard (statistically never)
  }
}

// ---------------------------------------------------------------- per-bucket counting sort
// emits PADDED csr (runs padded to x32 with sentinel NN), padded rowptr, true degree
__global__ __launch_bounds__(512) void k_sort(const unsigned int* __restrict__ bents,
                                              const int* __restrict__ bcur,
                                              int* __restrict__ prowptr,
                                              int* __restrict__ degv,
                                              unsigned short* __restrict__ csr16) {
  __shared__ int lh[256], lsc[256], plsc[256], lc2[256];
  const int b = blockIdx.x, t = threadIdx.x;
  const int base = b * MAXBE;
  const int nb = min(bcur[b] - base, MAXBE);
  const int pbase = b * MAXPB;

  if (t < 256) { lh[t] = 0; lc2[t] = 0; }
  __syncthreads();
  for (int i = t; i < nb; i += 512)
    atomicAdd(&lh[(bents[base + i] >> 16) & 255], 1);
  __syncthreads();
  if (t < 256) { lsc[t] = lh[t]; plsc[t] = (lh[t] + 31) & ~31; }
  __syncthreads();
  for (int off = 1; off < 256; off <<= 1) {
    int v = 0, pv = 0;
    if (t < 256 && t >= off) { v = lsc[t - off]; pv = plsc[t - off]; }
    __syncthreads();
    if (t < 256) { lsc[t] += v; plsc[t] += pv; }
    __syncthreads();
  }
  int ex = 0, pex = 0;
  if (t < 256) { ex = (t == 0) ? 0 : lsc[t - 1]; pex = (t == 0) ? 0 : plsc[t - 1]; }
  __syncthreads();
  if (t < 256) {
    lsc[t] = ex;
    plsc[t] = pex;
    int gnode = b * 256 + t;
    if (gnode < NN) { prowptr[gnode] = pbase + pex; degv[gnode] = lh[t]; }
  }
  __syncthreads();
  for (int i = t; i < nb; i += 512) {
    unsigned int e = bents[base + i];
    int dl = (e >> 16) & 255;
    int r = atomicAdd(&lc2[dl], 1);
    csr16[pbase + plsc[dl] + r] = (unsigned short)(e & 0xFFFF);
  }
  __syncthreads();
  if (t < 256) {
    int d = lh[t];
    int pd = (d + 31) & ~31;
    int o = pbase + plsc[t];
    for (int k = d; k < pd; ++k) csr16[o + k] = (unsigned short)NN;  // sentinel -> zero row
  }
}

// ---------------------------------------------------------------- embed: relu(LN(x@W+b)) -> bf16
__global__ __launch_bounds__(256) void k_embed(const float* __restrict__ x,
                                               const float* __restrict__ W,
                                               const float* __restrict__ b,
                                               const float* __restrict__ gamma,
                                               const float* __restrict__ beta,
                                               unsigned short* __restrict__ hout) {
  const int wid = threadIdx.x >> 6;
  const int lane = threadIdx.x & 63;
  const int node = blockIdx.x * 4 + wid;
  if (node >= NN) return;
  float xr[FIN];
#pragma unroll
  for (int k = 0; k < FIN; ++k) xr[k] = x[node * FIN + k];
  const int c0 = lane, c1 = lane + 64;
  float a0 = b[c0], a1 = b[c1];
#pragma unroll
  for (int k = 0; k < FIN; ++k) {
    a0 += xr[k] * W[k * DD + c0];
    a1 += xr[k] * W[k * DD + c1];
  }
  float s = a0 + a1;
#pragma unroll
  for (int m = 1; m < 64; m <<= 1) s += __shfl_xor(s, m, 64);
  float mean = s * (1.f / DD);
  float d0 = a0 - mean, d1 = a1 - mean;
  float v = d0 * d0 + d1 * d1;
#pragma unroll
  for (int m = 1; m < 64; m <<= 1) v += __shfl_xor(v, m, 64);
  float r = rsqrtf(v * (1.f / DD) + LN_EPS);
  hout[(size_t)node * DD + c0] = f2b(fmaxf(d0 * r * gamma[c0] + beta[c0], 0.f));
  hout[(size_t)node * DD + c1] = f2b(fmaxf(d1 * r * gamma[c1] + beta[c1], 0.f));
}

// ---------------------------------------------------------------- fused SAGE layer:
// aggregate (scatter-mean, gather form) -> LDS -> MFMA linear(256->128) + LN + ReLU
// block = 256 thr (4 waves), 64 nodes; wave w aggregates nodes w*16..w*16+15 then
// computes their 16 output rows via 16x16x32 MFMA.
template <int OUT_BF16>
__global__ __launch_bounds__(256) void k_sage(const unsigned short* __restrict__ hb,
                                              const int* __restrict__ prowptr,
                                              const int* __restrict__ degv,
                                              const unsigned short* __restrict__ csr16,
                                              const unsigned short* __restrict__ Wt,
                                              const float* __restrict__ bias,
                                              const float* __restrict__ gamma,
                                              const float* __restrict__ beta,
                                              void* __restrict__ outv) {
  __shared__ unsigned int smean[64 * 64];  // [node][dword^((node&7)<<2)] packed bf16x2
  const int tid = threadIdx.x;
  const int w = tid >> 6;
  const int l = tid & 63;
  const int nodeBase = blockIdx.x * 64;

  // ---- aggregation phase
  for (int j = 0; j < 16; ++j) {
    const int node = nodeBase + w * 16 + j;
    float alo = 0.f, ahi = 0.f;
    int deg = 0;
    if (node < NN) {
      const int pbeg = __builtin_amdgcn_readfirstlane(prowptr[node]);
      deg = __builtin_amdgcn_readfirstlane(degv[node]);
      const int nch = (deg + 31) >> 5;
      const unsigned int* __restrict__ cp =
          reinterpret_cast<const unsigned int*>(csr16 + pbeg);  // uniform -> scalar loads
      for (int c = 0; c < nch; ++c) {
#pragma unroll
        for (int q = 0; q < 16; ++q) {
          unsigned int pair = cp[c * 16 + q];
          const unsigned int* r0 =
              reinterpret_cast<const unsigned int*>(hb + (size_t)(pair & 0xFFFFu) * DD);
          const unsigned int* r1 =
              reinterpret_cast<const unsigned int*>(hb + (size_t)(pair >> 16) * DD);
          unsigned int u0 = r0[l];
          unsigned int u1 = r1[l];
          alo += __uint_as_float(u0 << 16) + __uint_as_float(u1 << 16);
          ahi += __uint_as_float(u0 & 0xFFFF0000u) + __uint_as_float(u1 & 0xFFFF0000u);
        }
      }
    }
    float inv = 1.f / (float)max(deg, 1);
    unsigned int o =
        ((unsigned int)f2b(ahi * inv) << 16) | (unsigned int)f2b(alo * inv);
    const int nl = w * 16 + j;
    smean[nl * 64 + (l ^ ((nl & 7) << 2))] = o;
  }
  __syncthreads();

  // ---- MFMA phase
  const int c16 = l & 15;
  const int kg = l >> 4;
  const int rowBase = nodeBase + w * 16;
  const unsigned short* arow_self = hb + (size_t)(rowBase + c16) * DD;
  const unsigned int* mrow = smean + (size_t)(w * 16 + c16) * 64;

  f32x4 acc[8];
#pragma unroll
  for (int t = 0; t < 8; ++t) acc[t] = (f32x4){0.f, 0.f, 0.f, 0.f};

#pragma unroll
  for (int kc = 0; kc < 8; ++kc) {
    bf16x8 a;
    if (kc < 4) {
      a = *reinterpret_cast<const bf16x8*>(arow_self + kc * 32 + kg * 8);
    } else {
      int d0 = (((kc & 3) * 16 + kg * 4) ^ ((c16 & 7) << 2));
      uint4 um = *reinterpret_cast<const uint4*>(mrow + d0);
      a = __builtin_bit_cast(bf16x8, um);
    }
#pragma unroll
    for (int t = 0; t < 8; ++t) {
      bf16x8 b = *reinterpret_cast<const bf16x8*>(
          Wt + (size_t)(t * 16 + c16) * 256 + kc * 32 + kg * 8);
      acc[t] = __builtin_amdgcn_mfma_f32_16x16x32_bf16(a, b, acc[t], 0, 0, 0);
    }
  }

  // epilogue: bias + LN + ReLU.  C/D: col = t*16 + c16, row = kg*4 + i
  float bv[8], gv[8], btv[8];
#pragma unroll
  for (int t = 0; t < 8; ++t) {
    int c = t * 16 + c16;
    bv[t] = bias[c]; gv[t] = gamma[c]; btv[t] = beta[c];
  }
#pragma unroll
  for (int t = 0; t < 8; ++t)
#pragma unroll
    for (int i = 0; i < 4; ++i) acc[t][i] += bv[t];

#pragma unroll
  for (int i = 0; i < 4; ++i) {
    float s = 0.f;
#pragma unroll
    for (int t = 0; t < 8; ++t) s += acc[t][i];
#pragma unroll
    for (int m = 1; m < 16; m <<= 1) s += __shfl_xor(s, m, 64);
    float mean = s * (1.f / DD);
    float v = 0.f;
#pragma unroll
    for (int t = 0; t < 8; ++t) {
      float d = acc[t][i] - mean;
      v += d * d;
    }
#pragma unroll
    for (int m = 1; m < 16; m <<= 1) v += __shfl_xor(v, m, 64);
    float r = rsqrtf(v * (1.f / DD) + LN_EPS);
    int onode = rowBase + kg * 4 + i;
    if (onode < NN) {
#pragma unroll
      for (int t = 0; t < 8; ++t) {
        float val = fmaxf((acc[t][i] - mean) * r * gv[t] + btv[t], 0.f);
        int c = t * 16 + c16;
        if (OUT_BF16) {
          ((unsigned short*)outv)[(size_t)onode * DD + c] = f2b(val);
        } else {
          ((float*)outv)[(size_t)onode * DD + c] = val;
        }
      }
    }
  }
}

// ---------------------------------------------------------------- graph pooling (mean+max)
__global__ __launch_bounds__(128) void k_pool1(const float* __restrict__ ne,
                                               const int* __restrict__ gstart,
                                               float* __restrict__ part) {
  const int g = blockIdx.x / PSEG;
  const int sg = blockIdx.x % PSEG;
  const int c = threadIdx.x;
  const int beg = gstart[g], end = gstart[g + 1];
  const int len = end - beg;
  const int per = (len + PSEG - 1) / PSEG;
  const int n0 = beg + sg * per;
  const int n1 = min(n0 + per, end);
  float s = 0.f, mx = -INFINITY;
  for (int n = n0; n < n1; ++n) {
    float v = ne[(size_t)n * DD + c];
    s += v;
    mx = fmaxf(mx, v);
  }
  part[(size_t)(g * PSEG + sg) * 256 + c] = s;
  part[(size_t)(g * PSEG + sg) * 256 + 128 + c] = mx;
}

__global__ __launch_bounds__(256) void k_pool2(const float* __restrict__ part,
                                               const int* __restrict__ gstart,
                                               float* __restrict__ gout) {
  const int g = blockIdx.x;
  const int c = threadIdx.x;
  const bool isMax = c >= 128;
  float acc = isMax ? -INFINITY : 0.f;
  for (int sg = 0; sg < PSEG; ++sg) {
    float v = part[(size_t)(g * PSEG + sg) * 256 + c];
    acc = isMax ? fmaxf(acc, v) : (acc + v);
  }
  if (!isMax) acc /= (float)max(gstart[g + 1] - gstart[g], 1);
  gout[(size_t)g * 256 + c] = acc;
}

// ---------------------------------------------------------------- launch
static inline size_t align_up(size_t v, size_t a) { return (v + a - 1) & ~(a - 1); }

extern "C" void kernel_launch(void* const* d_in, const int* in_sizes, int n_in,
                              void* d_out, int out_size, void* d_ws, size_t ws_size,
                              hipStream_t stream) {
  const float* x     = (const float*)d_in[0];
  const int*   ei    = (const int*)d_in[1];
  const int*   batch = (const int*)d_in[2];
  const float* W_emb = (const float*)d_in[3];
  const float* b_emb = (const float*)d_in[4];
  const float* g0    = (const float*)d_in[5];
  const float* bt0   = (const float*)d_in[6];
  const float* Wc1   = (const float*)d_in[7];
  const float* bc1   = (const float*)d_in[8];
  const float* g1    = (const float*)d_in[9];
  const float* bt1   = (const float*)d_in[10];
  const float* Wc2   = (const float*)d_in[11];
  const float* bc2   = (const float*)d_in[12];
  const float* g2    = (const float*)d_in[13];
  const float* bt2   = (const float*)d_in[14];
  const float* Wc3   = (const float*)d_in[15];
  const float* bc3   = (const float*)d_in[16];
  const float* g3    = (const float*)d_in[17];
  const float* bt3   = (const float*)d_in[18];

  const int* src = ei;
  const int* dst = ei + NE;

  float* out_node  = (float*)d_out;                     // N*D fp32
  float* out_graph = (float*)d_out + (size_t)NN * DD;   // G*256 fp32

  char* p = (char*)d_ws;
  auto alloc = [&](size_t bytes) { char* r = p; p += align_up(bytes, 256); return r; };
  int*            prowptr = (int*)alloc((size_t)NN * sizeof(int));
  int*            degv    = (int*)alloc((size_t)NN * sizeof(int));
  int*            bcur    = (int*)alloc(NB * sizeof(int));
  int*            gstart  = (int*)alloc((NG + 1) * sizeof(int));
  unsigned int*   bents   = (unsigned int*)alloc((size_t)NB * MAXBE * 4);
  unsigned short* csr16   = (unsigned short*)alloc((size_t)NB * MAXPB * 2);
  unsigned short* hba     = (unsigned short*)alloc((size_t)NNP * DD * 2);
  unsigned short* hbb     = (unsigned short*)alloc((size_t)NNP * DD * 2);
  unsigned short* Wt1     = (unsigned short*)alloc(128 * 256 * 2);
  unsigned short* Wt2     = (unsigned short*)alloc(128 * 256 * 2);
  unsigned short* Wt3     = (unsigned short*)alloc(128 * 256 * 2);
  float*          ppart   = (float*)alloc((size_t)NG * PSEG * 256 * sizeof(float));

  // prep: Wt x3, bcur init, gstart, pad zeroing   (1 dispatch)
  k_prep<<<388, 256, 0, stream>>>(Wc1, Wc2, Wc3, Wt1, Wt2, Wt3, bcur, batch, gstart,
                                  hba, hbb);
  // CSR build (2 dispatches)
  k_bscatter<<<(NE + CH - 1) / CH, 512, 0, stream>>>(src, dst, bcur, bents);
  k_sort<<<NB, 512, 0, stream>>>(bents, bcur, prowptr, degv, csr16);

  // embed -> bf16
  k_embed<<<NN / 4, 256, 0, stream>>>(x, W_emb, b_emb, g0, bt0, hba);

  const int SAGE_GRID = NNP / 64;  // 782
  k_sage<1><<<SAGE_GRID, 256, 0, stream>>>(hba, prowptr, degv, csr16, Wt1, bc1, g1, bt1, hbb);
  k_sage<1><<<SAGE_GRID, 256, 0, stream>>>(hbb, prowptr, degv, csr16, Wt2, bc2, g2, bt2, hba);
  k_sage<0><<<SAGE_GRID, 256, 0, stream>>>(hba, prowptr, degv, csr16, Wt3, bc3, g3, bt3, out_node);

  // pooling
  k_pool1<<<NG * PSEG, 128, 0, stream>>>(out_node, gstart, ppart);
  k_pool2<<<NG, 256, 0, stream>>>(ppart, gstart, out_graph);
}

// Round 7
// 277.221 us; speedup vs baseline: 3.6745x; 1.1436x over previous
//
#include <hip/hip_runtime.h>
#include <hip/hip_bf16.h>
#include <math.h>

#define NN 50000
#define NNP 50048          // padded rows (3128 tiles * 16)
#define NE 1600000
#define FIN 9
#define DD 128
#define NG 64
#define PSEG 16
#define LN_EPS 1e-5f

// binning: 196 buckets x 256 dst nodes, fixed regions
#define NB 196
#define BSHIFT 8
#define CH 8192            // edges per bscatter block
#define MAXBE 12288        // raw entries reserved per bucket (mean 8163, +45 sigma)
#define MAXPB 20480        // padded csr entries reserved per bucket

typedef __attribute__((ext_vector_type(8))) short bf16x8;
typedef __attribute__((ext_vector_type(4))) float f32x4;

static __device__ __forceinline__ unsigned short f2b(float f) {
  __hip_bfloat16 h = __float2bfloat16(f);
  return __builtin_bit_cast(unsigned short, h);
}

// ---------------------------------------------------------------- prep: Wt x3, bcur, gstart, pads
__global__ __launch_bounds__(256) void k_prep(const float* __restrict__ Wc1,
                                              const float* __restrict__ Wc2,
                                              const float* __restrict__ Wc3,
                                              unsigned short* __restrict__ Wt1,
                                              unsigned short* __restrict__ Wt2,
                                              unsigned short* __restrict__ Wt3,
                                              int* __restrict__ bcur,
                                              const int* __restrict__ batch,
                                              int* __restrict__ gstart,
                                              unsigned short* __restrict__ hba,
                                              unsigned short* __restrict__ hbb) {
  const int bid = blockIdx.x;
  const int t = threadIdx.x;
  if (bid < 384) {
    const float* W = (bid < 128) ? Wc1 : (bid < 256) ? Wc2 : Wc3;
    unsigned short* Wt = (bid < 128) ? Wt1 : (bid < 256) ? Wt2 : Wt3;
    int idx = (bid & 127) * 256 + t;  // 0..32767
    int k = idx >> 7;
    int n = idx & 127;
    Wt[n * 256 + k] = f2b(W[k * DD + n]);
  } else if (bid == 384) {
    if (t < NB) bcur[t] = t * MAXBE;
  } else if (bid == 385) {
    if (t <= NG) {
      int lo = 0, hi = NN;
      while (lo < hi) {
        int mid = (lo + hi) >> 1;
        if (batch[mid] < t) lo = mid + 1; else hi = mid;
      }
      gstart[t] = lo;
    }
  } else if (bid == 386) {
    unsigned int* p = reinterpret_cast<unsigned int*>(hba + (size_t)NN * DD);
    for (int i = t; i < (NNP - NN) * DD / 2; i += 256) p[i] = 0;
  } else {
    unsigned int* p = reinterpret_cast<unsigned int*>(hbb + (size_t)NN * DD);
    for (int i = t; i < (NNP - NN) * DD / 2; i += 256) p[i] = 0;
  }
}

// ---------------------------------------------------------------- binned scatter (fixed regions)
__global__ __launch_bounds__(512) void k_bscatter(const int* __restrict__ src,
                                                  const int* __restrict__ dst,
                                                  int* __restrict__ bcur,
                                                  unsigned int* __restrict__ bents) {
  __shared__ int lh[NB], lbase[NB], gbase[NB], lcnt[NB];
  __shared__ int stmp[256];
  __shared__ unsigned int sbuf[CH];
  const int t = threadIdx.x;
  const int e0 = blockIdx.x * CH;
  const int n = min(CH, NE - e0);

  for (int i = t; i < NB; i += 512) { lh[i] = 0; lcnt[i] = 0; }
  __syncthreads();

  unsigned int ent[16];
  int eb[16];
#pragma unroll
  for (int k = 0; k < 16; ++k) {
    int i = k * 512 + t;
    if (i < n) {
      int s = src[e0 + i], d = dst[e0 + i];
      ent[k] = ((unsigned)d << 16) | (unsigned)s;  // both < 65536
      eb[k] = d >> BSHIFT;
      atomicAdd(&lh[eb[k]], 1);
    } else {
      eb[k] = -1;
    }
  }
  __syncthreads();
  if (t < 256) stmp[t] = (t < NB) ? lh[t] : 0;
  __syncthreads();
  for (int off = 1; off < 256; off <<= 1) {
    int v = 0;
    if (t < 256 && t >= off) v = stmp[t - off];
    __syncthreads();
    if (t < 256) stmp[t] += v;
    __syncthreads();
  }
  if (t < NB) lbase[t] = (t == 0) ? 0 : stmp[t - 1];
  __syncthreads();
  if (t < NB && lh[t] > 0) gbase[t] = atomicAdd(&bcur[t], lh[t]);
  __syncthreads();
#pragma unroll
  for (int k = 0; k < 16; ++k) {
    if (eb[k] >= 0) {
      int r = atomicAdd(&lcnt[eb[k]], 1);
      sbuf[lbase[eb[k]] + r] = ent[k];
    }
  }
  __syncthreads();
  for (int i = t; i < n; i += 512) {
    unsigned int e = sbuf[i];
    int b = e >> 24;
    int pos = gbase[b] + (i - lbase[b]);
    if (pos < (b + 1) * MAXBE) bents[pos] = e;  // overflow guard (statistically never)
  }
}

// ---------------------------------------------------------------- per-bucket counting sort
// emits PADDED csr (runs padded to x32 with sentinel NN), padded rowptr, true degree
__global__ __launch_bounds__(512) void k_sort(const unsigned int* __restrict__ bents,
                                              const int* __restrict__ bcur,
                                              int* __restrict__ prowptr,
                                              int* __restrict__ degv,
                                              unsigned short* __restrict__ csr16) {
  __shared__ int lh[256], lsc[256], plsc[256], lc2[256];
  const int b = blockIdx.x, t = threadIdx.x;
  const int base = b * MAXBE;
  const int nb = min(bcur[b] - base, MAXBE);
  const int pbase = b * MAXPB;

  if (t < 256) { lh[t] = 0; lc2[t] = 0; }
  __syncthreads();
  for (int i = t; i < nb; i += 512)
    atomicAdd(&lh[(bents[base + i] >> 16) & 255], 1);
  __syncthreads();
  if (t < 256) { lsc[t] = lh[t]; plsc[t] = (lh[t] + 31) & ~31; }
  __syncthreads();
  for (int off = 1; off < 256; off <<= 1) {
    int v = 0, pv = 0;
    if (t < 256 && t >= off) { v = lsc[t - off]; pv = plsc[t - off]; }
    __syncthreads();
    if (t < 256) { lsc[t] += v; plsc[t] += pv; }
    __syncthreads();
  }
  int ex = 0, pex = 0;
  if (t < 256) { ex = (t == 0) ? 0 : lsc[t - 1]; pex = (t == 0) ? 0 : plsc[t - 1]; }
  __syncthreads();
  if (t < 256) {
    lsc[t] = ex;
    plsc[t] = pex;
    int gnode = b * 256 + t;
    if (gnode < NN) { prowptr[gnode] = pbase + pex; degv[gnode] = lh[t]; }
  }
  __syncthreads();
  for (int i = t; i < nb; i += 512) {
    unsigned int e = bents[base + i];
    int dl = (e >> 16) & 255;
    int r = atomicAdd(&lc2[dl], 1);
    csr16[pbase + plsc[dl] + r] = (unsigned short)(e & 0xFFFF);
  }
  __syncthreads();
  if (t < 256) {
    int d = lh[t];
    int pd = (d + 31) & ~31;
    int o = pbase + plsc[t];
    for (int k = d; k < pd; ++k) csr16[o + k] = (unsigned short)NN;  // sentinel -> zero row
  }
}

// ---------------------------------------------------------------- embed: relu(LN(x@W+b)) -> bf16
__global__ __launch_bounds__(256) void k_embed(const float* __restrict__ x,
                                               const float* __restrict__ W,
                                               const float* __restrict__ b,
                                               const float* __restrict__ gamma,
                                               const float* __restrict__ beta,
                                               unsigned short* __restrict__ hout) {
  const int wid = threadIdx.x >> 6;
  const int lane = threadIdx.x & 63;
  const int node = blockIdx.x * 4 + wid;
  if (node >= NN) return;
  float xr[FIN];
#pragma unroll
  for (int k = 0; k < FIN; ++k) xr[k] = x[node * FIN + k];
  const int c0 = lane, c1 = lane + 64;
  float a0 = b[c0], a1 = b[c1];
#pragma unroll
  for (int k = 0; k < FIN; ++k) {
    a0 += xr[k] * W[k * DD + c0];
    a1 += xr[k] * W[k * DD + c1];
  }
  float s = a0 + a1;
#pragma unroll
  for (int m = 1; m < 64; m <<= 1) s += __shfl_xor(s, m, 64);
  float mean = s * (1.f / DD);
  float d0 = a0 - mean, d1 = a1 - mean;
  float v = d0 * d0 + d1 * d1;
#pragma unroll
  for (int m = 1; m < 64; m <<= 1) v += __shfl_xor(v, m, 64);
  float r = rsqrtf(v * (1.f / DD) + LN_EPS);
  hout[(size_t)node * DD + c0] = f2b(fmaxf(d0 * r * gamma[c0] + beta[c0], 0.f));
  hout[(size_t)node * DD + c1] = f2b(fmaxf(d1 * r * gamma[c1] + beta[c1], 0.f));
}

// ---------------------------------------------------------------- fused SAGE layer, v2:
// block = 1024 thr (16 waves), 16 nodes. Wave w aggregates node (tile*16+w) with the
// full wave (round-5 structure: scalar CSR indices, saddr gathers) -> swizzled LDS.
// After barrier, wave 0 computes the 16-row MFMA linear(256->128) + LN + ReLU.
template <int OUT_BF16>
__global__ __launch_bounds__(1024) void k_sage(const unsigned short* __restrict__ hb,
                                               const int* __restrict__ prowptr,
                                               const int* __restrict__ degv,
                                               const unsigned short* __restrict__ csr16,
                                               const unsigned short* __restrict__ Wt,
                                               const float* __restrict__ bias,
                                               const float* __restrict__ gamma,
                                               const float* __restrict__ beta,
                                               void* __restrict__ outv) {
  __shared__ unsigned int smean[16 * 64];  // [node][dword^((node&7)<<2)] packed bf16x2
  const int tid = threadIdx.x;
  const int w = tid >> 6;        // wave = local node 0..15
  const int l = tid & 63;
  const int nodeBase = blockIdx.x * 16;
  const int node = nodeBase + w;

  // ---- aggregation: one node per wave
  float alo = 0.f, ahi = 0.f;
  int deg = 0;
  if (node < NN) {
    const int pbeg = __builtin_amdgcn_readfirstlane(prowptr[node]);
    deg = __builtin_amdgcn_readfirstlane(degv[node]);
    const int nch = (deg + 31) >> 5;
    const unsigned int* __restrict__ cp =
        reinterpret_cast<const unsigned int*>(csr16 + pbeg);  // uniform -> scalar loads
    for (int c = 0; c < nch; ++c) {
#pragma unroll
      for (int q = 0; q < 16; ++q) {
        unsigned int pair = cp[c * 16 + q];
        const unsigned int* r0 =
            reinterpret_cast<const unsigned int*>(hb + (size_t)(pair & 0xFFFFu) * DD);
        const unsigned int* r1 =
            reinterpret_cast<const unsigned int*>(hb + (size_t)(pair >> 16) * DD);
        unsigned int u0 = r0[l];
        unsigned int u1 = r1[l];
        alo += __uint_as_float(u0 << 16) + __uint_as_float(u1 << 16);
        ahi += __uint_as_float(u0 & 0xFFFF0000u) + __uint_as_float(u1 & 0xFFFF0000u);
      }
    }
  }
  float inv = 1.f / (float)max(deg, 1);
  unsigned int o = ((unsigned int)f2b(ahi * inv) << 16) | (unsigned int)f2b(alo * inv);
  smean[w * 64 + (l ^ ((w & 7) << 2))] = o;
  __syncthreads();

  if (w != 0) return;  // waves 1..15 retire; wave 0 does the 16-node MFMA tile

  // ---- MFMA phase (wave 0)
  const int c16 = l & 15;
  const int kg = l >> 4;
  const unsigned short* arow_self = hb + (size_t)(nodeBase + c16) * DD;
  const unsigned int* mrow = smean + (size_t)c16 * 64;

  f32x4 acc[8];
#pragma unroll
  for (int t = 0; t < 8; ++t) acc[t] = (f32x4){0.f, 0.f, 0.f, 0.f};

#pragma unroll
  for (int kc = 0; kc < 8; ++kc) {
    bf16x8 a;
    if (kc < 4) {
      a = *reinterpret_cast<const bf16x8*>(arow_self + kc * 32 + kg * 8);
    } else {
      int d0 = (((kc & 3) * 16 + kg * 4) ^ ((c16 & 7) << 2));
      uint4 um = *reinterpret_cast<const uint4*>(mrow + d0);
      a = __builtin_bit_cast(bf16x8, um);
    }
#pragma unroll
    for (int t = 0; t < 8; ++t) {
      bf16x8 b = *reinterpret_cast<const bf16x8*>(
          Wt + (size_t)(t * 16 + c16) * 256 + kc * 32 + kg * 8);
      acc[t] = __builtin_amdgcn_mfma_f32_16x16x32_bf16(a, b, acc[t], 0, 0, 0);
    }
  }

  // epilogue: bias + LN + ReLU.  C/D: col = t*16 + c16, row = kg*4 + i
  float bv[8], gv[8], btv[8];
#pragma unroll
  for (int t = 0; t < 8; ++t) {
    int c = t * 16 + c16;
    bv[t] = bias[c]; gv[t] = gamma[c]; btv[t] = beta[c];
  }
#pragma unroll
  for (int t = 0; t < 8; ++t)
#pragma unroll
    for (int i = 0; i < 4; ++i) acc[t][i] += bv[t];

#pragma unroll
  for (int i = 0; i < 4; ++i) {
    float s = 0.f;
#pragma unroll
    for (int t = 0; t < 8; ++t) s += acc[t][i];
#pragma unroll
    for (int m = 1; m < 16; m <<= 1) s += __shfl_xor(s, m, 64);
    float mean = s * (1.f / DD);
    float v = 0.f;
#pragma unroll
    for (int t = 0; t < 8; ++t) {
      float d = acc[t][i] - mean;
      v += d * d;
    }
#pragma unroll
    for (int m = 1; m < 16; m <<= 1) v += __shfl_xor(v, m, 64);
    float r = rsqrtf(v * (1.f / DD) + LN_EPS);
    int onode = nodeBase + kg * 4 + i;
    if (onode < NN) {
#pragma unroll
      for (int t = 0; t < 8; ++t) {
        float val = fmaxf((acc[t][i] - mean) * r * gv[t] + btv[t], 0.f);
        int c = t * 16 + c16;
        if (OUT_BF16) {
          ((unsigned short*)outv)[(size_t)onode * DD + c] = f2b(val);
        } else {
          ((float*)outv)[(size_t)onode * DD + c] = val;
        }
      }
    }
  }
}

// ---------------------------------------------------------------- graph pooling (mean+max)
__global__ __launch_bounds__(128) void k_pool1(const float* __restrict__ ne,
                                               const int* __restrict__ gstart,
                                               float* __restrict__ part) {
  const int g = blockIdx.x / PSEG;
  const int sg = blockIdx.x % PSEG;
  const int c = threadIdx.x;
  const int beg = gstart[g], end = gstart[g + 1];
  const int len = end - beg;
  const int per = (len + PSEG - 1) / PSEG;
  const int n0 = beg + sg * per;
  const int n1 = min(n0 + per, end);
  float s = 0.f, mx = -INFINITY;
  for (int n = n0; n < n1; ++n) {
    float v = ne[(size_t)n * DD + c];
    s += v;
    mx = fmaxf(mx, v);
  }
  part[(size_t)(g * PSEG + sg) * 256 + c] = s;
  part[(size_t)(g * PSEG + sg) * 256 + 128 + c] = mx;
}

__global__ __launch_bounds__(256) void k_pool2(const float* __restrict__ part,
                                               const int* __restrict__ gstart,
                                               float* __restrict__ gout) {
  const int g = blockIdx.x;
  const int c = threadIdx.x;
  const bool isMax = c >= 128;
  float acc = isMax ? -INFINITY : 0.f;
  for (int sg = 0; sg < PSEG; ++sg) {
    float v = part[(size_t)(g * PSEG + sg) * 256 + c];
    acc = isMax ? fmaxf(acc, v) : (acc + v);
  }
  if (!isMax) acc /= (float)max(gstart[g + 1] - gstart[g], 1);
  gout[(size_t)g * 256 + c] = acc;
}

// ---------------------------------------------------------------- launch
static inline size_t align_up(size_t v, size_t a) { return (v + a - 1) & ~(a - 1); }

extern "C" void kernel_launch(void* const* d_in, const int* in_sizes, int n_in,
                              void* d_out, int out_size, void* d_ws, size_t ws_size,
                              hipStream_t stream) {
  const float* x     = (const float*)d_in[0];
  const int*   ei    = (const int*)d_in[1];
  const int*   batch = (const int*)d_in[2];
  const float* W_emb = (const float*)d_in[3];
  const float* b_emb = (const float*)d_in[4];
  const float* g0    = (const float*)d_in[5];
  const float* bt0   = (const float*)d_in[6];
  const float* Wc1   = (const float*)d_in[7];
  const float* bc1   = (const float*)d_in[8];
  const float* g1    = (const float*)d_in[9];
  const float* bt1   = (const float*)d_in[10];
  const float* Wc2   = (const float*)d_in[11];
  const float* bc2   = (const float*)d_in[12];
  const float* g2    = (const float*)d_in[13];
  const float* bt2   = (const float*)d_in[14];
  const float* Wc3   = (const float*)d_in[15];
  const float* bc3   = (const float*)d_in[16];
  const float* g3    = (const float*)d_in[17];
  const float* bt3   = (const float*)d_in[18];

  const int* src = ei;
  const int* dst = ei + NE;

  float* out_node  = (float*)d_out;                     // N*D fp32
  float* out_graph = (float*)d_out + (size_t)NN * DD;   // G*256 fp32

  char* p = (char*)d_ws;
  auto alloc = [&](size_t bytes) { char* r = p; p += align_up(bytes, 256); return r; };
  int*            prowptr = (int*)alloc((size_t)NN * sizeof(int));
  int*            degv    = (int*)alloc((size_t)NN * sizeof(int));
  int*            bcur    = (int*)alloc(NB * sizeof(int));
  int*            gstart  = (int*)alloc((NG + 1) * sizeof(int));
  unsigned int*   bents   = (unsigned int*)alloc((size_t)NB * MAXBE * 4);
  unsigned short* csr16   = (unsigned short*)alloc((size_t)NB * MAXPB * 2);
  unsigned short* hba     = (unsigned short*)alloc((size_t)NNP * DD * 2);
  unsigned short* hbb     = (unsigned short*)alloc((size_t)NNP * DD * 2);
  unsigned short* Wt1     = (unsigned short*)alloc(128 * 256 * 2);
  unsigned short* Wt2     = (unsigned short*)alloc(128 * 256 * 2);
  unsigned short* Wt3     = (unsigned short*)alloc(128 * 256 * 2);
  float*          ppart   = (float*)alloc((size_t)NG * PSEG * 256 * sizeof(float));

  // prep: Wt x3, bcur init, gstart, pad zeroing   (1 dispatch)
  k_prep<<<388, 256, 0, stream>>>(Wc1, Wc2, Wc3, Wt1, Wt2, Wt3, bcur, batch, gstart,
                                  hba, hbb);
  // CSR build (2 dispatches)
  k_bscatter<<<(NE + CH - 1) / CH, 512, 0, stream>>>(src, dst, bcur, bents);
  k_sort<<<NB, 512, 0, stream>>>(bents, bcur, prowptr, degv, csr16);

  // embed -> bf16
  k_embed<<<NN / 4, 256, 0, stream>>>(x, W_emb, b_emb, g0, bt0, hba);

  const int SAGE_GRID = NNP / 16;  // 3128
  k_sage<1><<<SAGE_GRID, 1024, 0, stream>>>(hba, prowptr, degv, csr16, Wt1, bc1, g1, bt1, hbb);
  k_sage<1><<<SAGE_GRID, 1024, 0, stream>>>(hbb, prowptr, degv, csr16, Wt2, bc2, g2, bt2, hba);
  k_sage<0><<<SAGE_GRID, 1024, 0, stream>>>(hba, prowptr, degv, csr16, Wt3, bc3, g3, bt3, out_node);

  // pooling
  k_pool1<<<NG * PSEG, 128, 0, stream>>>(out_node, gstart, ppart);
  k_pool2<<<NG, 256, 0, stream>>>(ppart, gstart, out_graph);
}

// Round 8
// 265.584 us; speedup vs baseline: 3.8355x; 1.0438x over previous
//
#include <hip/hip_runtime.h>
#include <hip/hip_bf16.h>
#include <math.h>

#define NN 50000
#define NNP 50048          // padded rows
#define NE 1600000
#define FIN 9
#define DD 128
#define NG 64
#define PSEG 16
#define LN_EPS 1e-5f

// binning: 196 buckets x 256 dst nodes, fixed regions
#define NB 196
#define BSHIFT 8
#define CH 8192            // edges per bscatter block
#define MAXBE 12288        // raw entries reserved per bucket (mean 8163, +45 sigma)
#define MAXPB 20480        // padded csr entries reserved per bucket

typedef __attribute__((ext_vector_type(8))) short bf16x8;
typedef __attribute__((ext_vector_type(4))) float f32x4;
typedef __attribute__((ext_vector_type(2))) float f32x2;

static __device__ __forceinline__ unsigned short f2b(float f) {
  __hip_bfloat16 h = __float2bfloat16(f);
  return __builtin_bit_cast(unsigned short, h);
}
static __device__ __forceinline__ unsigned char f2e4m3(float f) {
  int r = __builtin_amdgcn_cvt_pk_fp8_f32(f, f, 0, false);
  return (unsigned char)(r & 0xFF);
}

// ---------------------------------------------------------------- prep: Wt x3, bcur, gstart, pads
__global__ __launch_bounds__(256) void k_prep(const float* __restrict__ Wc1,
                                              const float* __restrict__ Wc2,
                                              const float* __restrict__ Wc3,
                                              unsigned short* __restrict__ Wt1,
                                              unsigned short* __restrict__ Wt2,
                                              unsigned short* __restrict__ Wt3,
                                              int* __restrict__ bcur,
                                              const int* __restrict__ batch,
                                              int* __restrict__ gstart,
                                              unsigned short* __restrict__ hba,
                                              unsigned short* __restrict__ hbb,
                                              unsigned char* __restrict__ h8,
                                              unsigned int* __restrict__ hmb) {
  const int bid = blockIdx.x;
  const int t = threadIdx.x;
  if (bid < 384) {
    const float* W = (bid < 128) ? Wc1 : (bid < 256) ? Wc2 : Wc3;
    unsigned short* Wt = (bid < 128) ? Wt1 : (bid < 256) ? Wt2 : Wt3;
    int idx = (bid & 127) * 256 + t;  // 0..32767
    int k = idx >> 7;
    int n = idx & 127;
    Wt[n * 256 + k] = f2b(W[k * DD + n]);
  } else if (bid == 384) {
    if (t < NB) bcur[t] = t * MAXBE;
    if (t >= 128 && t <= 128 + NG) {
      int g = t - 128;
      int lo = 0, hi = NN;
      while (lo < hi) {
        int mid = (lo + hi) >> 1;
        if (batch[mid] < g) lo = mid + 1; else hi = mid;
      }
      gstart[g] = lo;
    }
  } else if (bid == 385) {
    unsigned int* p = reinterpret_cast<unsigned int*>(hba + (size_t)NN * DD);
    for (int i = t; i < (NNP - NN) * DD / 2; i += 256) p[i] = 0;
  } else if (bid == 386) {
    unsigned int* p = reinterpret_cast<unsigned int*>(hbb + (size_t)NN * DD);
    for (int i = t; i < (NNP - NN) * DD / 2; i += 256) p[i] = 0;
  } else if (bid == 387) {
    unsigned int* p = reinterpret_cast<unsigned int*>(h8 + (size_t)NN * DD);
    for (int i = t; i < (NNP - NN) * DD / 4; i += 256) p[i] = 0;
  } else {
    unsigned int* p = hmb + (size_t)NN * 64;
    for (int i = t; i < (NNP - NN) * 64; i += 256) p[i] = 0;
  }
}

// ---------------------------------------------------------------- binned scatter (fixed regions)
__global__ __launch_bounds__(512) void k_bscatter(const int* __restrict__ src,
                                                  const int* __restrict__ dst,
                                                  int* __restrict__ bcur,
                                                  unsigned int* __restrict__ bents) {
  __shared__ int lh[NB], lbase[NB], gbase[NB], lcnt[NB];
  __shared__ int stmp[256];
  __shared__ unsigned int sbuf[CH];
  const int t = threadIdx.x;
  const int e0 = blockIdx.x * CH;
  const int n = min(CH, NE - e0);

  for (int i = t; i < NB; i += 512) { lh[i] = 0; lcnt[i] = 0; }
  __syncthreads();

  unsigned int ent[16];
  int eb[16];
#pragma unroll
  for (int k = 0; k < 16; ++k) {
    int i = k * 512 + t;
    if (i < n) {
      int s = src[e0 + i], d = dst[e0 + i];
      ent[k] = ((unsigned)d << 16) | (unsigned)s;  // both < 65536
      eb[k] = d >> BSHIFT;
      atomicAdd(&lh[eb[k]], 1);
    } else {
      eb[k] = -1;
    }
  }
  __syncthreads();
  if (t < 256) stmp[t] = (t < NB) ? lh[t] : 0;
  __syncthreads();
  for (int off = 1; off < 256; off <<= 1) {
    int v = 0;
    if (t < 256 && t >= off) v = stmp[t - off];
    __syncthreads();
    if (t < 256) stmp[t] += v;
    __syncthreads();
  }
  if (t < NB) lbase[t] = (t == 0) ? 0 : stmp[t - 1];
  __syncthreads();
  if (t < NB && lh[t] > 0) gbase[t] = atomicAdd(&bcur[t], lh[t]);
  __syncthreads();
#pragma unroll
  for (int k = 0; k < 16; ++k) {
    if (eb[k] >= 0) {
      int r = atomicAdd(&lcnt[eb[k]], 1);
      sbuf[lbase[eb[k]] + r] = ent[k];
    }
  }
  __syncthreads();
  for (int i = t; i < n; i += 512) {
    unsigned int e = sbuf[i];
    int b = e >> 24;
    int pos = gbase[b] + (i - lbase[b]);
    if (pos < (b + 1) * MAXBE) bents[pos] = e;  // overflow guard (statistically never)
  }
}

// ---------------------------------------------------------------- per-bucket counting sort
__global__ __launch_bounds__(512) void k_sort(const unsigned int* __restrict__ bents,
                                              const int* __restrict__ bcur,
                                              int* __restrict__ prowptr,
                                              int* __restrict__ degv,
                                              unsigned short* __restrict__ csr16) {
  __shared__ int lh[256], lsc[256], plsc[256], lc2[256];
  const int b = blockIdx.x, t = threadIdx.x;
  const int base = b * MAXBE;
  const int nb = min(bcur[b] - base, MAXBE);
  const int pbase = b * MAXPB;

  if (t < 256) { lh[t] = 0; lc2[t] = 0; }
  __syncthreads();
  for (int i = t; i < nb; i += 512)
    atomicAdd(&lh[(bents[base + i] >> 16) & 255], 1);
  __syncthreads();
  if (t < 256) { lsc[t] = lh[t]; plsc[t] = (lh[t] + 31) & ~31; }
  __syncthreads();
  for (int off = 1; off < 256; off <<= 1) {
    int v = 0, pv = 0;
    if (t < 256 && t >= off) { v = lsc[t - off]; pv = plsc[t - off]; }
    __syncthreads();
    if (t < 256) { lsc[t] += v; plsc[t] += pv; }
    __syncthreads();
  }
  int ex = 0, pex = 0;
  if (t < 256) { ex = (t == 0) ? 0 : lsc[t - 1]; pex = (t == 0) ? 0 : plsc[t - 1]; }
  __syncthreads();
  if (t < 256) {
    lsc[t] = ex;
    plsc[t] = pex;
    int gnode = b * 256 + t;
    if (gnode < NN) { prowptr[gnode] = pbase + pex; degv[gnode] = lh[t]; }
  }
  __syncthreads();
  for (int i = t; i < nb; i += 512) {
    unsigned int e = bents[base + i];
    int dl = (e >> 16) & 255;
    int r = atomicAdd(&lc2[dl], 1);
    csr16[pbase + plsc[dl] + r] = (unsigned short)(e & 0xFFFF);
  }
  __syncthreads();
  if (t < 256) {
    int d = lh[t];
    int pd = (d + 31) & ~31;
    int o = pbase + plsc[t];
    for (int k = d; k < pd; ++k) csr16[o + k] = (unsigned short)NN;  // sentinel -> zero row
  }
}

// ---------------------------------------------------------------- embed: relu(LN(x@W+b)) -> bf16 + fp8
__global__ __launch_bounds__(256) void k_embed(const float* __restrict__ x,
                                               const float* __restrict__ W,
                                               const float* __restrict__ b,
                                               const float* __restrict__ gamma,
                                               const float* __restrict__ beta,
                                               unsigned short* __restrict__ hout,
                                               unsigned char* __restrict__ h8) {
  const int wid = threadIdx.x >> 6;
  const int lane = threadIdx.x & 63;
  const int node = blockIdx.x * 4 + wid;
  if (node >= NN) return;
  float xr[FIN];
#pragma unroll
  for (int k = 0; k < FIN; ++k) xr[k] = x[node * FIN + k];
  const int c0 = lane, c1 = lane + 64;
  float a0 = b[c0], a1 = b[c1];
#pragma unroll
  for (int k = 0; k < FIN; ++k) {
    a0 += xr[k] * W[k * DD + c0];
    a1 += xr[k] * W[k * DD + c1];
  }
  float s = a0 + a1;
#pragma unroll
  for (int m = 1; m < 64; m <<= 1) s += __shfl_xor(s, m, 64);
  float mean = s * (1.f / DD);
  float d0 = a0 - mean, d1 = a1 - mean;
  float v = d0 * d0 + d1 * d1;
#pragma unroll
  for (int m = 1; m < 64; m <<= 1) v += __shfl_xor(v, m, 64);
  float r = rsqrtf(v * (1.f / DD) + LN_EPS);
  float o0 = fmaxf(d0 * r * gamma[c0] + beta[c0], 0.f);
  float o1 = fmaxf(d1 * r * gamma[c1] + beta[c1], 0.f);
  hout[(size_t)node * DD + c0] = f2b(o0);
  hout[(size_t)node * DD + c1] = f2b(o1);
  h8[(size_t)node * DD + c0] = f2e4m3(o0);
  h8[(size_t)node * DD + c1] = f2e4m3(o1);
}

// ---------------------------------------------------------------- scatter-mean (fp8 gather)
// one WAVE per node; scalar CSR indices; saddr gathers of 128B fp8 rows
__global__ __launch_bounds__(256) void k_aggr(const unsigned char* __restrict__ h8,
                                              const int* __restrict__ prowptr,
                                              const int* __restrict__ degv,
                                              const unsigned short* __restrict__ csr16,
                                              unsigned int* __restrict__ hmb) {
  const int wid = __builtin_amdgcn_readfirstlane(threadIdx.x >> 6);
  const int l = threadIdx.x & 63;
  const int node = blockIdx.x * 4 + wid;   // grid covers exactly NN
  const int pbeg = __builtin_amdgcn_readfirstlane(prowptr[node]);
  const int deg = __builtin_amdgcn_readfirstlane(degv[node]);
  const int nch = (deg + 31) >> 5;
  const unsigned int* __restrict__ cp =
      reinterpret_cast<const unsigned int*>(csr16 + pbeg);  // uniform -> scalar loads
  float a0 = 0.f, a1 = 0.f;
  for (int c = 0; c < nch; ++c) {
#pragma unroll
    for (int q = 0; q < 16; ++q) {
      unsigned int pair = cp[c * 16 + q];
      const unsigned short* r0 =
          reinterpret_cast<const unsigned short*>(h8 + (size_t)(pair & 0xFFFFu) * DD);
      const unsigned short* r1 =
          reinterpret_cast<const unsigned short*>(h8 + (size_t)(pair >> 16) * DD);
      unsigned int u0 = r0[l];
      unsigned int u1 = r1[l];
      f32x2 d0 = __builtin_amdgcn_cvt_pk_f32_fp8((int)u0, false);
      f32x2 d1 = __builtin_amdgcn_cvt_pk_f32_fp8((int)u1, false);
      a0 += d0.x + d1.x;
      a1 += d0.y + d1.y;
    }
  }
  float inv = 1.f / (float)max(deg, 1);
  unsigned int o = ((unsigned int)f2b(a1 * inv) << 16) | (unsigned int)f2b(a0 * inv);
  hmb[(size_t)node * 64 + l] = o;   // channels 2l (low), 2l+1 (high)
}

// ---------------------------------------------------------------- MFMA linear(256->128)+LN+ReLU
template <int OUT_BF16>
__global__ __launch_bounds__(256) void k_lin_mfma(const unsigned short* __restrict__ hb,
                                                  const unsigned short* __restrict__ hmb,
                                                  const unsigned short* __restrict__ Wt,
                                                  const float* __restrict__ bias,
                                                  const float* __restrict__ gamma,
                                                  const float* __restrict__ beta,
                                                  void* __restrict__ outv,
                                                  unsigned char* __restrict__ h8out) {
  const int tid = threadIdx.x;
  const int w = tid >> 6;
  const int l = tid & 63;
  const int c16 = l & 15;
  const int kg = l >> 4;
  const int rowBase = blockIdx.x * 64 + w * 16;

  f32x4 acc[8];
#pragma unroll
  for (int t = 0; t < 8; ++t) acc[t] = (f32x4){0.f, 0.f, 0.f, 0.f};

  const unsigned short* arow_self = hb + (size_t)(rowBase + c16) * DD;
  const unsigned short* arow_mean = hmb + (size_t)(rowBase + c16) * DD;

#pragma unroll
  for (int kc = 0; kc < 8; ++kc) {
    const unsigned short* arow = (kc < 4) ? arow_self : arow_mean;
    bf16x8 a = *reinterpret_cast<const bf16x8*>(arow + (kc & 3) * 32 + kg * 8);
#pragma unroll
    for (int t = 0; t < 8; ++t) {
      bf16x8 b = *reinterpret_cast<const bf16x8*>(
          Wt + (size_t)(t * 16 + c16) * 256 + kc * 32 + kg * 8);
      acc[t] = __builtin_amdgcn_mfma_f32_16x16x32_bf16(a, b, acc[t], 0, 0, 0);
    }
  }

  float bv[8], gv[8], btv[8];
#pragma unroll
  for (int t = 0; t < 8; ++t) {
    int c = t * 16 + c16;
    bv[t] = bias[c]; gv[t] = gamma[c]; btv[t] = beta[c];
  }
#pragma unroll
  for (int t = 0; t < 8; ++t)
#pragma unroll
    for (int i = 0; i < 4; ++i) acc[t][i] += bv[t];

#pragma unroll
  for (int i = 0; i < 4; ++i) {
    float s = 0.f;
#pragma unroll
    for (int t = 0; t < 8; ++t) s += acc[t][i];
#pragma unroll
    for (int m = 1; m < 16; m <<= 1) s += __shfl_xor(s, m, 64);
    float mean = s * (1.f / DD);
    float v = 0.f;
#pragma unroll
    for (int t = 0; t < 8; ++t) {
      float d = acc[t][i] - mean;
      v += d * d;
    }
#pragma unroll
    for (int m = 1; m < 16; m <<= 1) v += __shfl_xor(v, m, 64);
    float r = rsqrtf(v * (1.f / DD) + LN_EPS);
    int onode = rowBase + kg * 4 + i;
    if (onode < NN) {
#pragma unroll
      for (int t = 0; t < 8; ++t) {
        float val = fmaxf((acc[t][i] - mean) * r * gv[t] + btv[t], 0.f);
        int c = t * 16 + c16;
        if (OUT_BF16) {
          ((unsigned short*)outv)[(size_t)onode * DD + c] = f2b(val);
          h8out[(size_t)onode * DD + c] = f2e4m3(val);
        } else {
          ((float*)outv)[(size_t)onode * DD + c] = val;
        }
      }
    }
  }
}

// ---------------------------------------------------------------- graph pooling (mean+max)
__global__ __launch_bounds__(128) void k_pool1(const float* __restrict__ ne,
                                               const int* __restrict__ gstart,
                                               float* __restrict__ part) {
  const int g = blockIdx.x / PSEG;
  const int sg = blockIdx.x % PSEG;
  const int c = threadIdx.x;
  const int beg = gstart[g], end = gstart[g + 1];
  const int len = end - beg;
  const int per = (len + PSEG - 1) / PSEG;
  const int n0 = beg + sg * per;
  const int n1 = min(n0 + per, end);
  float s = 0.f, mx = -INFINITY;
  for (int n = n0; n < n1; ++n) {
    float v = ne[(size_t)n * DD + c];
    s += v;
    mx = fmaxf(mx, v);
  }
  part[(size_t)(g * PSEG + sg) * 256 + c] = s;
  part[(size_t)(g * PSEG + sg) * 256 + 128 + c] = mx;
}

__global__ __launch_bounds__(256) void k_pool2(const float* __restrict__ part,
                                               const int* __restrict__ gstart,
                                               float* __restrict__ gout) {
  const int g = blockIdx.x;
  const int c = threadIdx.x;
  const bool isMax = c >= 128;
  float acc = isMax ? -INFINITY : 0.f;
  for (int sg = 0; sg < PSEG; ++sg) {
    float v = part[(size_t)(g * PSEG + sg) * 256 + c];
    acc = isMax ? fmaxf(acc, v) : (acc + v);
  }
  if (!isMax) acc /= (float)max(gstart[g + 1] - gstart[g], 1);
  gout[(size_t)g * 256 + c] = acc;
}

// ---------------------------------------------------------------- launch
static inline size_t align_up(size_t v, size_t a) { return (v + a - 1) & ~(a - 1); }

extern "C" void kernel_launch(void* const* d_in, const int* in_sizes, int n_in,
                              void* d_out, int out_size, void* d_ws, size_t ws_size,
                              hipStream_t stream) {
  const float* x     = (const float*)d_in[0];
  const int*   ei    = (const int*)d_in[1];
  const int*   batch = (const int*)d_in[2];
  const float* W_emb = (const float*)d_in[3];
  const float* b_emb = (const float*)d_in[4];
  const float* g0    = (const float*)d_in[5];
  const float* bt0   = (const float*)d_in[6];
  const float* Wc1   = (const float*)d_in[7];
  const float* bc1   = (const float*)d_in[8];
  const float* g1    = (const float*)d_in[9];
  const float* bt1   = (const float*)d_in[10];
  const float* Wc2   = (const float*)d_in[11];
  const float* bc2   = (const float*)d_in[12];
  const float* g2    = (const float*)d_in[13];
  const float* bt2   = (const float*)d_in[14];
  const float* Wc3   = (const float*)d_in[15];
  const float* bc3   = (const float*)d_in[16];
  const float* g3    = (const float*)d_in[17];
  const float* bt3   = (const float*)d_in[18];

  const int* src = ei;
  const int* dst = ei + NE;

  float* out_node  = (float*)d_out;                     // N*D fp32
  float* out_graph = (float*)d_out + (size_t)NN * DD;   // G*256 fp32

  char* p = (char*)d_ws;
  auto alloc = [&](size_t bytes) { char* r = p; p += align_up(bytes, 256); return r; };
  int*            prowptr = (int*)alloc((size_t)NN * sizeof(int));
  int*            degv    = (int*)alloc((size_t)NN * sizeof(int));
  int*            bcur    = (int*)alloc(NB * sizeof(int));
  int*            gstart  = (int*)alloc((NG + 1) * sizeof(int));
  unsigned int*   bents   = (unsigned int*)alloc((size_t)NB * MAXBE * 4);
  unsigned short* csr16   = (unsigned short*)alloc((size_t)NB * MAXPB * 2);
  unsigned short* hba     = (unsigned short*)alloc((size_t)NNP * DD * 2);
  unsigned short* hbb     = (unsigned short*)alloc((size_t)NNP * DD * 2);
  unsigned char*  h8      = (unsigned char*)alloc((size_t)NNP * DD);
  unsigned int*   hmb     = (unsigned int*)alloc((size_t)NNP * 64 * 4);
  unsigned short* Wt1     = (unsigned short*)alloc(128 * 256 * 2);
  unsigned short* Wt2     = (unsigned short*)alloc(128 * 256 * 2);
  unsigned short* Wt3     = (unsigned short*)alloc(128 * 256 * 2);
  float*          ppart   = (float*)alloc((size_t)NG * PSEG * 256 * sizeof(float));

  // prep: Wt x3, bcur init, gstart, pad zeroing   (1 dispatch)
  k_prep<<<388, 256, 0, stream>>>(Wc1, Wc2, Wc3, Wt1, Wt2, Wt3, bcur, batch, gstart,
                                  hba, hbb, h8, hmb);
  // CSR build (2 dispatches)
  k_bscatter<<<(NE + CH - 1) / CH, 512, 0, stream>>>(src, dst, bcur, bents);
  k_sort<<<NB, 512, 0, stream>>>(bents, bcur, prowptr, degv, csr16);

  // embed -> bf16 + fp8
  k_embed<<<NN / 4, 256, 0, stream>>>(x, W_emb, b_emb, g0, bt0, hba, h8);

  const int LIN_GRID = NNP / 64;   // 782
  const int AGGR_GRID = NN / 4;    // 12500 (wave per node)
  // layer 1
  k_aggr<<<AGGR_GRID, 256, 0, stream>>>(h8, prowptr, degv, csr16, hmb);
  k_lin_mfma<1><<<LIN_GRID, 256, 0, stream>>>(hba, (unsigned short*)hmb, Wt1, bc1, g1, bt1, hbb, h8);
  // layer 2
  k_aggr<<<AGGR_GRID, 256, 0, stream>>>(h8, prowptr, degv, csr16, hmb);
  k_lin_mfma<1><<<LIN_GRID, 256, 0, stream>>>(hbb, (unsigned short*)hmb, Wt2, bc2, g2, bt2, hba, h8);
  // layer 3
  k_aggr<<<AGGR_GRID, 256, 0, stream>>>(h8, prowptr, degv, csr16, hmb);
  k_lin_mfma<0><<<LIN_GRID, 256, 0, stream>>>(hba, (unsigned short*)hmb, Wt3, bc3, g3, bt3, out_node, h8);

  // pooling
  k_pool1<<<NG * PSEG, 128, 0, stream>>>(out_node, gstart, ppart);
  k_pool2<<<NG, 256, 0, stream>>>(ppart, gstart, out_graph);
}